// Round 1
// baseline (1709.025 us; speedup 1.0000x reference)
//
#include <hip/hip_runtime.h>
#include <math.h>

// Problem constants (fixed by the reference)
#define TOK    2048      // B*S
#define DMODEL 1024
#define NHEAD  16
#define HDIM   64
#define NEXP   8
#define DFFN   4096

__device__ __forceinline__ float sigmoidf_(float x) { return 1.f / (1.f + expf(-x)); }

// block = 256 threads (4 waves). Broadcast result to all threads.
__device__ __forceinline__ float blockReduceSum256(float val) {
  __shared__ float ws_[4];
  #pragma unroll
  for (int off = 32; off; off >>= 1) val += __shfl_down(val, off);
  int lane = threadIdx.x & 63, w = threadIdx.x >> 6;
  if (lane == 0) ws_[w] = val;
  __syncthreads();
  float r = ws_[0] + ws_[1] + ws_[2] + ws_[3];
  __syncthreads();   // allow LDS reuse on next call
  return r;
}

// ---------------------------------------------------------------------------
// Generic dense GEMM: C[M,N] = A[M,K] @ W[K,N]  (row-major, M,N,K % 64 == 0)
// EPI==0: C = acc
// EPI==1: C = sigmoid(acc + bias[n]) * mul[m,n]      (attention gate fusion)
// Tile 64x64, K-step 32, 256 threads, 4x4 microtile per thread.
// ---------------------------------------------------------------------------
template<int EPI>
__global__ __launch_bounds__(256) void gemm_kernel(
    const float* __restrict__ A, const float* __restrict__ W,
    const float* __restrict__ bias, const float* __restrict__ mul,
    float* __restrict__ C, int M, int N, int K) {
  __shared__ float As[32][68];   // [k][m]  (stride 68 keeps float4-aligned rows)
  __shared__ float Bs[32][68];   // [k][n]
  int tid = threadIdx.x;
  int tx = tid & 15, ty = tid >> 4;
  int row0 = blockIdx.y * 64, col0 = blockIdx.x * 64;
  float acc[4][4] = {};
  for (int k0 = 0; k0 < K; k0 += 32) {
    #pragma unroll
    for (int p = 0; p < 2; ++p) {               // A tile 64x32
      int r  = (tid >> 3) + p * 32;
      int kk = (tid & 7) * 4;
      float4 av = *(const float4*)&A[(size_t)(row0 + r) * K + k0 + kk];
      As[kk+0][r] = av.x; As[kk+1][r] = av.y; As[kk+2][r] = av.z; As[kk+3][r] = av.w;
    }
    #pragma unroll
    for (int p = 0; p < 2; ++p) {               // B tile 32x64
      int kk = (tid >> 4) + p * 16;
      *(float4*)&Bs[kk][(tid & 15) * 4] =
          *(const float4*)&W[(size_t)(k0 + kk) * N + col0 + (tid & 15) * 4];
    }
    __syncthreads();
    #pragma unroll
    for (int kk = 0; kk < 32; ++kk) {
      float a[4], b[4];
      #pragma unroll
      for (int i = 0; i < 4; ++i) a[i] = As[kk][ty*4+i];
      #pragma unroll
      for (int j = 0; j < 4; ++j) b[j] = Bs[kk][tx*4+j];
      #pragma unroll
      for (int i = 0; i < 4; ++i)
        #pragma unroll
        for (int j = 0; j < 4; ++j) acc[i][j] += a[i] * b[j];
    }
    __syncthreads();
  }
  #pragma unroll
  for (int i = 0; i < 4; ++i) {
    int r = row0 + ty*4 + i;
    int c = col0 + tx*4;
    float4 o;
    if (EPI == 0) {
      o = make_float4(acc[i][0], acc[i][1], acc[i][2], acc[i][3]);
    } else {
      o.x = sigmoidf_(acc[i][0] + bias[c+0]) * mul[(size_t)r*N + c+0];
      o.y = sigmoidf_(acc[i][1] + bias[c+1]) * mul[(size_t)r*N + c+1];
      o.z = sigmoidf_(acc[i][2] + bias[c+2]) * mul[(size_t)r*N + c+2];
      o.w = sigmoidf_(acc[i][3] + bias[c+3]) * mul[(size_t)r*N + c+3];
    }
    *(float4*)&C[(size_t)r*N + c] = o;
  }
}

// ---------------------------------------------------------------------------
// Flash attention, fp32. grid = (S/64, H, B), block = 256.
// Q,K,V are token-major [TOK, DMODEL]; head h lives at columns [h*64, h*64+64).
// Includes the per-(head,query) sigmoid scale gate folded into score scaling.
// ---------------------------------------------------------------------------
__global__ __launch_bounds__(256) void attn_kernel(
    const float* __restrict__ Q, const float* __restrict__ K,
    const float* __restrict__ V, const float* __restrict__ scale_w,
    float* __restrict__ O) {
  int qt = blockIdx.x, hh = blockIdx.y, b = blockIdx.z;
  __shared__ float Qs[64][65];
  __shared__ float KS[64][65];   // K-tile during QK^T, then P-tile (union saves LDS)
  __shared__ float Vs[64][65];
  __shared__ float m_s[64], l_s[64], alpha_s[64], scale_s[64], sw[64];
  int tid = threadIdx.x;
  int tx = tid & 15, ty = tid >> 4;
  const size_t baseq = ((size_t)b * 1024 + (size_t)qt * 64) * 1024 + hh * 64;
  #pragma unroll
  for (int p = 0; p < 16; ++p) {     // load Q tile (coalesced rows)
    int idx = p * 256 + tid;
    int r = idx >> 6, c = idx & 63;
    Qs[r][c] = Q[baseq + (size_t)r * 1024 + c];
  }
  if (tid < 64) sw[tid] = scale_w[hh * 64 + tid];
  __syncthreads();
  if (tid < 64) {                    // per-row dynamic scale gate
    float dot = 0.f;
    #pragma unroll
    for (int d = 0; d < 64; ++d) dot += Qs[tid][d] * sw[d];
    scale_s[tid] = 2.f * sigmoidf_(dot);
    m_s[tid] = -1e30f;
    l_s[tid] = 0.f;
  }
  float o[4][4] = {};
  for (int kt = 0; kt < 16; ++kt) {
    __syncthreads();                 // prev PV done before overwriting K/V
    const size_t basek = ((size_t)b * 1024 + (size_t)kt * 64) * 1024 + hh * 64;
    #pragma unroll
    for (int p = 0; p < 16; ++p) {
      int idx = p * 256 + tid;
      int r = idx >> 6, c = idx & 63;
      KS[r][c] = K[basek + (size_t)r * 1024 + c];
      Vs[r][c] = V[basek + (size_t)r * 1024 + c];
    }
    __syncthreads();
    float s_acc[4][4] = {};
    for (int d = 0; d < 64; ++d) {   // S = Q @ K^T
      float qv[4], kv[4];
      #pragma unroll
      for (int i = 0; i < 4; ++i) qv[i] = Qs[ty*4+i][d];
      #pragma unroll
      for (int j = 0; j < 4; ++j) kv[j] = KS[tx*4+j][d];
      #pragma unroll
      for (int i = 0; i < 4; ++i)
        #pragma unroll
        for (int j = 0; j < 4; ++j) s_acc[i][j] += qv[i] * kv[j];
    }
    __syncthreads();                 // all K reads done; KS becomes P
    #pragma unroll
    for (int i = 0; i < 4; ++i) {
      float sc = scale_s[ty*4+i] * 0.125f;   // 1/sqrt(64) * gate
      #pragma unroll
      for (int j = 0; j < 4; ++j) KS[ty*4+i][tx*4+j] = s_acc[i][j] * sc;
    }
    __syncthreads();
    if (tid < 64) {                  // online softmax, one thread per row
      float mold = m_s[tid];
      float rmax = mold;
      #pragma unroll
      for (int j = 0; j < 64; ++j) rmax = fmaxf(rmax, KS[tid][j]);
      float alpha = expf(mold - rmax);
      float rsum = 0.f;
      #pragma unroll
      for (int j = 0; j < 64; ++j) {
        float pv = expf(KS[tid][j] - rmax);
        KS[tid][j] = pv;
        rsum += pv;
      }
      l_s[tid] = l_s[tid] * alpha + rsum;
      m_s[tid] = rmax;
      alpha_s[tid] = alpha;
    }
    __syncthreads();
    float ar[4];
    #pragma unroll
    for (int i = 0; i < 4; ++i) ar[i] = alpha_s[ty*4+i];
    #pragma unroll
    for (int i = 0; i < 4; ++i)
      #pragma unroll
      for (int j = 0; j < 4; ++j) o[i][j] *= ar[i];
    for (int kr = 0; kr < 64; ++kr) {  // O += P @ V
      float pv[4], vv[4];
      #pragma unroll
      for (int i = 0; i < 4; ++i) pv[i] = KS[ty*4+i][kr];
      #pragma unroll
      for (int j = 0; j < 4; ++j) vv[j] = Vs[kr][tx*4+j];
      #pragma unroll
      for (int i = 0; i < 4; ++i)
        #pragma unroll
        for (int j = 0; j < 4; ++j) o[i][j] += pv[i] * vv[j];
    }
  }
  __syncthreads();
  #pragma unroll
  for (int i = 0; i < 4; ++i) {
    int qr = ty*4 + i;
    float invl = 1.f / l_s[qr];
    size_t orow = ((size_t)b*1024 + (size_t)qt*64 + qr) * 1024 + hh*64 + tx*4;
    *(float4*)&O[orow] = make_float4(o[i][0]*invl, o[i][1]*invl, o[i][2]*invl, o[i][3]*invl);
  }
}

// ---------------------------------------------------------------------------
// x = LN(a + b) * g + beta, D=1024, one block per token
// ---------------------------------------------------------------------------
__global__ __launch_bounds__(256) void ln_add_kernel(
    const float* __restrict__ A, const float* __restrict__ Bp,
    const float* __restrict__ g, const float* __restrict__ beta,
    float* __restrict__ out) {
  int t = blockIdx.x, tid = threadIdx.x;
  const float* a = A + (size_t)t * DMODEL;
  const float* b = Bp + (size_t)t * DMODEL;
  float v[4]; float s = 0.f;
  #pragma unroll
  for (int i = 0; i < 4; ++i) { int d = tid + i*256; v[i] = a[d] + b[d]; s += v[i]; }
  s = blockReduceSum256(s);
  float mean = s * (1.f/1024.f);
  float q = 0.f;
  #pragma unroll
  for (int i = 0; i < 4; ++i) { float df = v[i]-mean; q += df*df; }
  q = blockReduceSum256(q);
  float rstd = rsqrtf(q*(1.f/1024.f) + 1e-5f);
  #pragma unroll
  for (int i = 0; i < 4; ++i) {
    int d = tid + i*256;
    out[(size_t)t*DMODEL + d] = (v[i]-mean)*rstd*g[d] + beta[d];
  }
}

// ---------------------------------------------------------------------------
// MoE router: logits = x @ mgw + mgb; e_sel = max(index of top-2 logits).
// One wave per token (4 waves/block).
// ---------------------------------------------------------------------------
__global__ __launch_bounds__(256) void moe_gate_kernel(
    const float* __restrict__ X, const float* __restrict__ gw,
    const float* __restrict__ gb, int* __restrict__ e_sel) {
  int wave = threadIdx.x >> 6, lane = threadIdx.x & 63;
  int token = blockIdx.x * 4 + wave;
  const float* x = X + (size_t)token * DMODEL;
  float acc[NEXP] = {};
  for (int d = lane; d < DMODEL; d += 64) {
    float xv = x[d];
    const float* gr = gw + (size_t)d * NEXP;
    #pragma unroll
    for (int e = 0; e < NEXP; ++e) acc[e] += xv * gr[e];
  }
  #pragma unroll
  for (int e = 0; e < NEXP; ++e) {
    #pragma unroll
    for (int off = 32; off; off >>= 1) acc[e] += __shfl_down(acc[e], off);
  }
  if (lane == 0) {
    float lg[NEXP];
    #pragma unroll
    for (int e = 0; e < NEXP; ++e) lg[e] = acc[e] + gb[e];
    int i1 = 0;
    for (int e = 1; e < NEXP; ++e) if (lg[e] > lg[i1]) i1 = e;       // ties: lower idx
    int i2 = -1;
    for (int e = 0; e < NEXP; ++e) {
      if (e == i1) continue;
      if (i2 < 0 || lg[e] > lg[i2]) i2 = e;
    }
    e_sel[token] = (i1 > i2) ? i1 : i2;
  }
}

// Single-block count + scan + scatter: perm groups token ids by expert.
__global__ __launch_bounds__(256) void moe_group_kernel(
    const int* __restrict__ e_sel, int* __restrict__ perm,
    int* __restrict__ g_offs, int* __restrict__ g_counts) {
  __shared__ int cnt[NEXP], offs[NEXP], cur[NEXP];
  int tid = threadIdx.x;
  if (tid < NEXP) cnt[tid] = 0;
  __syncthreads();
  for (int t = tid; t < TOK; t += 256) atomicAdd(&cnt[e_sel[t]], 1);
  __syncthreads();
  if (tid == 0) {
    int run = 0;
    for (int e = 0; e < NEXP; ++e) { offs[e] = run; cur[e] = run; run += cnt[e]; }
  }
  __syncthreads();
  if (tid < NEXP) { g_offs[tid] = offs[tid]; g_counts[tid] = cnt[tid]; }
  for (int t = tid; t < TOK; t += 256) {
    int pos = atomicAdd(&cur[e_sel[t]], 1);
    perm[pos] = t;
  }
}

// ---------------------------------------------------------------------------
// MoE FFN stage 1 (grouped GEMM): H[tok] = x[tok] @ w1[e] + b1[e]
// grid = (DFFN/64, 32, NEXP); blocks beyond the expert's token count exit.
// ---------------------------------------------------------------------------
__global__ __launch_bounds__(256) void moe_ffn1_kernel(
    const float* __restrict__ X, const float* __restrict__ W1,
    const float* __restrict__ B1, const int* __restrict__ perm,
    const int* __restrict__ offs, const int* __restrict__ counts,
    float* __restrict__ H) {
  int e = blockIdx.z;
  int n_e = counts[e];
  int tm = blockIdx.y;
  if (tm * 64 >= n_e) return;
  __shared__ float As[32][68];
  __shared__ float Bs[32][68];
  __shared__ int toks[64];
  int tid = threadIdx.x;
  if (tid < 64) {
    int idx = tm * 64 + tid;
    toks[tid] = (idx < n_e) ? perm[offs[e] + idx] : -1;
  }
  __syncthreads();
  int tx = tid & 15, ty = tid >> 4;
  int col0 = blockIdx.x * 64;
  const float* W = W1 + (size_t)e * DMODEL * DFFN;
  float acc[4][4] = {};
  for (int k0 = 0; k0 < DMODEL; k0 += 32) {
    #pragma unroll
    for (int p = 0; p < 2; ++p) {
      int r  = (tid >> 3) + p * 32;
      int kk = (tid & 7) * 4;
      int tok = toks[r];
      float4 av = make_float4(0.f, 0.f, 0.f, 0.f);
      if (tok >= 0) av = *(const float4*)&X[(size_t)tok * DMODEL + k0 + kk];
      As[kk+0][r] = av.x; As[kk+1][r] = av.y; As[kk+2][r] = av.z; As[kk+3][r] = av.w;
    }
    #pragma unroll
    for (int p = 0; p < 2; ++p) {
      int kk = (tid >> 4) + p * 16;
      *(float4*)&Bs[kk][(tid & 15) * 4] =
          *(const float4*)&W[(size_t)(k0 + kk) * DFFN + col0 + (tid & 15) * 4];
    }
    __syncthreads();
    #pragma unroll
    for (int kk = 0; kk < 32; ++kk) {
      float a[4], b[4];
      #pragma unroll
      for (int i = 0; i < 4; ++i) a[i] = As[kk][ty*4+i];
      #pragma unroll
      for (int j = 0; j < 4; ++j) b[j] = Bs[kk][tx*4+j];
      #pragma unroll
      for (int i = 0; i < 4; ++i)
        #pragma unroll
        for (int j = 0; j < 4; ++j) acc[i][j] += a[i] * b[j];
    }
    __syncthreads();
  }
  const float* b1e = B1 + (size_t)e * DFFN;
  #pragma unroll
  for (int i = 0; i < 4; ++i) {
    int tok = toks[ty*4 + i];
    if (tok < 0) continue;
    int c = col0 + tx*4;
    float4 o = make_float4(acc[i][0] + b1e[c+0], acc[i][1] + b1e[c+1],
                           acc[i][2] + b1e[c+2], acc[i][3] + b1e[c+3]);
    *(float4*)&H[(size_t)tok * DFFN + c] = o;
  }
}

// LN over DFF (per selected expert's gains) + exact-erf GELU, in place.
__global__ __launch_bounds__(256) void moe_ln_gelu_kernel(
    float* __restrict__ H, const float* __restrict__ ln_g,
    const float* __restrict__ ln_b, const int* __restrict__ e_sel) {
  int t = blockIdx.x, tid = threadIdx.x;
  int e = e_sel[t];
  float* h = H + (size_t)t * DFFN;
  float v[16]; float s = 0.f;
  #pragma unroll
  for (int i = 0; i < 16; ++i) { v[i] = h[tid + i*256]; s += v[i]; }
  s = blockReduceSum256(s);
  float mean = s * (1.f/4096.f);
  float q = 0.f;
  #pragma unroll
  for (int i = 0; i < 16; ++i) { float df = v[i]-mean; q += df*df; }
  q = blockReduceSum256(q);
  float rstd = rsqrtf(q*(1.f/4096.f) + 1e-5f);
  const float* gg = ln_g + (size_t)e * DFFN;
  const float* bb = ln_b + (size_t)e * DFFN;
  #pragma unroll
  for (int i = 0; i < 16; ++i) {
    int d = tid + i*256;
    float x = (v[i]-mean)*rstd*gg[d] + bb[d];
    h[d] = 0.5f * x * (1.f + erff(x * 0.7071067811865475f));   // exact GELU
  }
}

// MoE FFN stage 2: Y[tok] = (H[tok] @ w2[e] + b2[e]) * rs[e] + x[tok]
__global__ __launch_bounds__(256) void moe_ffn2_kernel(
    const float* __restrict__ H, const float* __restrict__ W2,
    const float* __restrict__ B2, const float* __restrict__ rs,
    const float* __restrict__ X, const int* __restrict__ perm,
    const int* __restrict__ offs, const int* __restrict__ counts,
    float* __restrict__ Y) {
  int e = blockIdx.z;
  int n_e = counts[e];
  int tm = blockIdx.y;
  if (tm * 64 >= n_e) return;
  __shared__ float As[32][68];
  __shared__ float Bs[32][68];
  __shared__ int toks[64];
  int tid = threadIdx.x;
  if (tid < 64) {
    int idx = tm * 64 + tid;
    toks[tid] = (idx < n_e) ? perm[offs[e] + idx] : -1;
  }
  __syncthreads();
  int tx = tid & 15, ty = tid >> 4;
  int col0 = blockIdx.x * 64;
  const float* W = W2 + (size_t)e * DFFN * DMODEL;
  float acc[4][4] = {};
  for (int k0 = 0; k0 < DFFN; k0 += 32) {
    #pragma unroll
    for (int p = 0; p < 2; ++p) {
      int r  = (tid >> 3) + p * 32;
      int kk = (tid & 7) * 4;
      int tok = toks[r];
      float4 av = make_float4(0.f, 0.f, 0.f, 0.f);
      if (tok >= 0) av = *(const float4*)&H[(size_t)tok * DFFN + k0 + kk];
      As[kk+0][r] = av.x; As[kk+1][r] = av.y; As[kk+2][r] = av.z; As[kk+3][r] = av.w;
    }
    #pragma unroll
    for (int p = 0; p < 2; ++p) {
      int kk = (tid >> 4) + p * 16;
      *(float4*)&Bs[kk][(tid & 15) * 4] =
          *(const float4*)&W[(size_t)(k0 + kk) * DMODEL + col0 + (tid & 15) * 4];
    }
    __syncthreads();
    #pragma unroll
    for (int kk = 0; kk < 32; ++kk) {
      float a[4], b[4];
      #pragma unroll
      for (int i = 0; i < 4; ++i) a[i] = As[kk][ty*4+i];
      #pragma unroll
      for (int j = 0; j < 4; ++j) b[j] = Bs[kk][tx*4+j];
      #pragma unroll
      for (int i = 0; i < 4; ++i)
        #pragma unroll
        for (int j = 0; j < 4; ++j) acc[i][j] += a[i] * b[j];
    }
    __syncthreads();
  }
  const float* b2e = B2 + (size_t)e * DMODEL;
  float rse = rs[e];
  #pragma unroll
  for (int i = 0; i < 4; ++i) {
    int tok = toks[ty*4 + i];
    if (tok < 0) continue;
    int c = col0 + tx*4;
    float4 o;
    o.x = (acc[i][0] + b2e[c+0]) * rse + X[(size_t)tok*DMODEL + c+0];
    o.y = (acc[i][1] + b2e[c+1]) * rse + X[(size_t)tok*DMODEL + c+1];
    o.z = (acc[i][2] + b2e[c+2]) * rse + X[(size_t)tok*DMODEL + c+2];
    o.w = (acc[i][3] + b2e[c+3]) * rse + X[(size_t)tok*DMODEL + c+3];
    *(float4*)&Y[(size_t)tok * DMODEL + c] = o;
  }
}

// ---------------------------------------------------------------------------
extern "C" void kernel_launch(void* const* d_in, const int* in_sizes, int n_in,
                              void* d_out, int out_size, void* d_ws, size_t ws_size,
                              hipStream_t stream) {
  (void)in_sizes; (void)n_in; (void)out_size; (void)ws_size;
  const float* src    = (const float*)d_in[0];
  const float* qw     = (const float*)d_in[1];
  const float* kw     = (const float*)d_in[2];
  const float* vw     = (const float*)d_in[3];
  const float* ow     = (const float*)d_in[4];
  const float* gate_w = (const float*)d_in[5];
  const float* gate_b = (const float*)d_in[6];
  const float* scale_w= (const float*)d_in[7];
  const float* n1_g   = (const float*)d_in[8];
  const float* n1_b   = (const float*)d_in[9];
  const float* n2_g   = (const float*)d_in[10];
  const float* n2_b   = (const float*)d_in[11];
  const float* mgw    = (const float*)d_in[12];
  const float* mgb    = (const float*)d_in[13];
  const float* w1     = (const float*)d_in[14];
  const float* b1     = (const float*)d_in[15];
  const float* ln_g   = (const float*)d_in[16];
  const float* ln_b   = (const float*)d_in[17];
  const float* w2     = (const float*)d_in[18];
  const float* b2     = (const float*)d_in[19];
  const float* rs     = (const float*)d_in[20];

  char* ws = (char*)d_ws;
  const size_t MB = 1024 * 1024;
  float* q    = (float*)(ws + 0 * MB);    // [TOK, D]
  float* k    = (float*)(ws + 8 * MB);
  float* v    = (float*)(ws + 16 * MB);
  float* ao   = (float*)(ws + 24 * MB);   // attention out, token-major
  float* h    = (float*)(ws + 32 * MB);   // [TOK, DFF] = 32 MB
  int* e_sel  = (int*)(ws + 64 * MB);
  int* perm   = e_sel + TOK;
  int* offs   = perm + TOK;
  int* counts = offs + NEXP;
  // aliases (lifetimes do not overlap):
  float* gbuf = q;   // gated attention output (q dead after attn_kernel)
  float* proj = k;   // attn_out after ow       (k dead after attn_kernel)
  float* x    = v;   // post-LN1 activations    (v dead after attn_kernel)
  float* y    = q;   // MoE output              (gbuf dead after ow GEMM)

  dim3 blk(256);
  // QKV projections
  gemm_kernel<0><<<dim3(16, 32), blk, 0, stream>>>(src, qw, nullptr, nullptr, q, TOK, DMODEL, DMODEL);
  gemm_kernel<0><<<dim3(16, 32), blk, 0, stream>>>(src, kw, nullptr, nullptr, k, TOK, DMODEL, DMODEL);
  gemm_kernel<0><<<dim3(16, 32), blk, 0, stream>>>(src, vw, nullptr, nullptr, v, TOK, DMODEL, DMODEL);
  // flash attention with dynamic scale gate
  attn_kernel<<<dim3(16, NHEAD, 2), blk, 0, stream>>>(q, k, v, scale_w, ao);
  // gate = sigmoid(ao @ gate_w + gate_b); gbuf = ao * gate  (fused epilogue)
  gemm_kernel<1><<<dim3(16, 32), blk, 0, stream>>>(ao, gate_w, gate_b, ao, gbuf, TOK, DMODEL, DMODEL);
  // proj = gbuf @ ow
  gemm_kernel<0><<<dim3(16, 32), blk, 0, stream>>>(gbuf, ow, nullptr, nullptr, proj, TOK, DMODEL, DMODEL);
  // x = LN(src + proj)
  ln_add_kernel<<<dim3(TOK), blk, 0, stream>>>(src, proj, n1_g, n1_b, x);
  // router: e_sel = max(top-2 index); wsum == 1 so only e_sel's FFN is needed
  moe_gate_kernel<<<dim3(TOK / 4), blk, 0, stream>>>(x, mgw, mgb, e_sel);
  moe_group_kernel<<<dim3(1), blk, 0, stream>>>(e_sel, perm, offs, counts);
  // grouped FFN on selected experts only
  moe_ffn1_kernel<<<dim3(DFFN / 64, 32, NEXP), blk, 0, stream>>>(x, w1, b1, perm, offs, counts, h);
  moe_ln_gelu_kernel<<<dim3(TOK), blk, 0, stream>>>(h, ln_g, ln_b, e_sel);
  moe_ffn2_kernel<<<dim3(DMODEL / 64, 32, NEXP), blk, 0, stream>>>(h, w2, b2, rs, x, perm, offs, counts, y);
  // out = LN(x + y)
  ln_add_kernel<<<dim3(TOK), blk, 0, stream>>>(x, y, n2_g, n2_b, (float*)d_out);
}

// Round 2
// 1023.249 us; speedup vs baseline: 1.6702x; 1.6702x over previous
//
#include <hip/hip_runtime.h>
#include <math.h>

// Problem constants (fixed by the reference)
#define TOK    2048      // B*S
#define DMODEL 1024
#define NHEAD  16
#define HDIM   64
#define NEXP   8
#define DFFN   4096

typedef unsigned short u16;
typedef __attribute__((ext_vector_type(8))) short short8;   // 8 bf16 (4 VGPRs)
typedef __attribute__((ext_vector_type(4))) float floatx4;  // MFMA C/D

__device__ __forceinline__ float sigmoidf_(float x) { return 1.f / (1.f + expf(-x)); }

__device__ __forceinline__ u16 f2bf(float f) {               // RNE fp32->bf16
  union { float f; unsigned u; } v; v.f = f;
  unsigned r = v.u + 0x7FFFu + ((v.u >> 16) & 1u);
  return (u16)(r >> 16);
}
__device__ __forceinline__ float bf2f(u16 h) {
  union { unsigned u; float f; } v; v.u = ((unsigned)h) << 16; return v.f;
}

// async global->LDS, 16B per lane; LDS dest = wave-uniform base + lane*16
__device__ __forceinline__ void gload16(const void* g, void* l) {
  __builtin_amdgcn_global_load_lds((const __attribute__((address_space(1))) void*)g,
                                   (__attribute__((address_space(3))) void*)l, 16, 0, 0);
}

// block = 256 threads (4 waves). Broadcast result to all threads.
__device__ __forceinline__ float blockReduceSum256(float val) {
  __shared__ float ws_[4];
  #pragma unroll
  for (int off = 32; off; off >>= 1) val += __shfl_down(val, off);
  int lane = threadIdx.x & 63, w = threadIdx.x >> 6;
  if (lane == 0) ws_[w] = val;
  __syncthreads();
  float r = ws_[0] + ws_[1] + ws_[2] + ws_[3];
  __syncthreads();
  return r;
}

// ---------------------------------------------------------------------------
// fp32 -> (hi, lo) bf16 split, elementwise. grid = n/1024, 4 floats/thread.
// ---------------------------------------------------------------------------
__global__ __launch_bounds__(256) void split_kernel(
    const float* __restrict__ X, u16* __restrict__ Hi, u16* __restrict__ Lo) {
  const int i = blockIdx.x * 256 + threadIdx.x;
  const float4 v = ((const float4*)X)[i];
  const float f[4] = {v.x, v.y, v.z, v.w};
  union { u16 s[4]; uint2 u; } h, l;
  #pragma unroll
  for (int j = 0; j < 4; ++j) {
    h.s[j] = f2bf(f[j]);
    l.s[j] = f2bf(f[j] - bf2f(h.s[j]));
  }
  ((uint2*)Hi)[i] = h.u;
  ((uint2*)Lo)[i] = l.u;
}

// ---------------------------------------------------------------------------
// Weight convert+transpose: W[K][N] fp32 -> Wt_hi[N][K] bf16 (+ optional lo).
// blockIdx.z = batch (expert); strides K*N. 32x32 LDS tile.
// ---------------------------------------------------------------------------
template<bool LO>
__global__ __launch_bounds__(256) void wt_conv_kernel(
    const float* __restrict__ W, u16* __restrict__ Whi, u16* __restrict__ Wlo,
    int K, int N) {
  const size_t z = blockIdx.z;
  W   += z * (size_t)K * N;
  Whi += z * (size_t)K * N;
  if (LO) Wlo += z * (size_t)K * N;
  __shared__ float tile[32][33];
  const int n0 = blockIdx.x * 32, k0 = blockIdx.y * 32;
  const int r = threadIdx.x >> 3, c4 = (threadIdx.x & 7) * 4;
  const float4 v = *(const float4*)&W[(size_t)(k0 + r) * N + n0 + c4];
  tile[r][c4+0] = v.x; tile[r][c4+1] = v.y; tile[r][c4+2] = v.z; tile[r][c4+3] = v.w;
  __syncthreads();
  union { u16 s[4]; uint2 u; } h, l;
  #pragma unroll
  for (int j = 0; j < 4; ++j) {
    const float f = tile[c4 + j][r];
    h.s[j] = f2bf(f);
    if (LO) l.s[j] = f2bf(f - bf2f(h.s[j]));
  }
  *(uint2*)&Whi[(size_t)(n0 + r) * K + k0 + c4] = h.u;
  if (LO) *(uint2*)&Wlo[(size_t)(n0 + r) * K + k0 + c4] = l.u;
}

// ---------------------------------------------------------------------------
// Split-precision bf16 MFMA GEMM: C[M,N] = A[M,K] @ W[K,N], where
// A is given as (Ahi,Alo) bf16 [M][K] and W as transposed (Whi,Wlo) bf16 [N][K].
// acc += Ah*Wh + Al*Wh + Ah*Wl  (error ~2^-18, protects MoE routing).
// 128x128 tile, BK=64, 4 waves (2x2 of 64x64), 16x16x32 MFMA.
// LDS chunk-swizzle: chunk c at row m holds k-chunk (c ^ (m&7)) -> 2-way max.
// EPI 0: Cf = acc (fp32).  EPI 1: g = sigmoid(acc+bias[n])*mul[m,n] -> Chi/Clo.
// ---------------------------------------------------------------------------
template<int EPI>
__global__ __launch_bounds__(256, 2) void gemm_split_kernel(
    const u16* __restrict__ Ahi, const u16* __restrict__ Alo,
    const u16* __restrict__ Whi, const u16* __restrict__ Wlo,
    const float* __restrict__ bias, const float* __restrict__ mul,
    float* __restrict__ Cf, u16* __restrict__ Chi, u16* __restrict__ Clo,
    int M, int N, int K) {
  __shared__ u16 Ah[128*64], Al[128*64], Bh[128*64], Bl[128*64];   // 64 KB
  const int tid = threadIdx.x;
  const int lane = tid & 63, wave = tid >> 6;
  const int row0 = blockIdx.y * 128, col0 = blockIdx.x * 128;
  const int wm = (wave & 1) * 64, wn = (wave >> 1) * 64;
  const int mr = tid >> 3;                       // staging row 0..31 (+p*32)
  const int ksrc = (tid & 7) ^ ((tid >> 3) & 7); // swizzled source k-chunk
  const floatx4 zero = {0.f, 0.f, 0.f, 0.f};
  floatx4 acc[4][4];
  #pragma unroll
  for (int i = 0; i < 4; ++i)
    #pragma unroll
    for (int j = 0; j < 4; ++j) acc[i][j] = zero;

  for (int k0 = 0; k0 < K; k0 += 64) {
    __syncthreads();
    #pragma unroll
    for (int p = 0; p < 4; ++p) {
      const int m = p * 32 + mr;
      const size_t ga = (size_t)(row0 + m) * K + (k0 + ksrc * 8);
      const size_t gb = (size_t)(col0 + m) * K + (k0 + ksrc * 8);
      const size_t off = (size_t)(p * 256 + wave * 64) * 16;   // bytes
      gload16(Ahi + ga, (char*)Ah + off);
      gload16(Alo + ga, (char*)Al + off);
      gload16(Whi + gb, (char*)Bh + off);
      gload16(Wlo + gb, (char*)Bl + off);
    }
    __syncthreads();   // compiler drains vmcnt before s_barrier
    #pragma unroll
    for (int kk = 0; kk < 2; ++kk) {
      short8 ah[4], al[4], bh[4], bl[4];
      #pragma unroll
      for (int i = 0; i < 4; ++i) {
        const int ml = wm + i * 16 + (lane & 15);
        const int cm = (kk * 4 + (lane >> 4)) ^ (ml & 7);
        ah[i] = *(const short8*)&Ah[ml * 64 + cm * 8];
        al[i] = *(const short8*)&Al[ml * 64 + cm * 8];
        const int nl = wn + i * 16 + (lane & 15);
        const int cn = (kk * 4 + (lane >> 4)) ^ (nl & 7);
        bh[i] = *(const short8*)&Bh[nl * 64 + cn * 8];
        bl[i] = *(const short8*)&Bl[nl * 64 + cn * 8];
      }
      #pragma unroll
      for (int i = 0; i < 4; ++i)
        #pragma unroll
        for (int j = 0; j < 4; ++j) {
          acc[i][j] = __builtin_amdgcn_mfma_f32_16x16x32_bf16(ah[i], bh[j], acc[i][j], 0, 0, 0);
          acc[i][j] = __builtin_amdgcn_mfma_f32_16x16x32_bf16(al[i], bh[j], acc[i][j], 0, 0, 0);
          acc[i][j] = __builtin_amdgcn_mfma_f32_16x16x32_bf16(ah[i], bl[j], acc[i][j], 0, 0, 0);
        }
    }
  }
  const int cl = lane & 15, quad = lane >> 4;
  #pragma unroll
  for (int i = 0; i < 4; ++i)
    #pragma unroll
    for (int j = 0; j < 4; ++j) {
      const int col = col0 + wn + j * 16 + cl;
      #pragma unroll
      for (int r = 0; r < 4; ++r) {
        const int row = row0 + wm + i * 16 + quad * 4 + r;
        const float v = acc[i][j][r];
        if (EPI == 0) {
          Cf[(size_t)row * N + col] = v;
        } else {
          const float s = sigmoidf_(v + bias[col]);
          const float g = s * mul[(size_t)row * N + col];
          const u16 hh = f2bf(g);
          Chi[(size_t)row * N + col] = hh;
          Clo[(size_t)row * N + col] = f2bf(g - bf2f(hh));
        }
      }
    }
}

// ---------------------------------------------------------------------------
// Grouped MoE GEMM, plain bf16 MFMA (post-routing; bf16 error is safe here).
// A[T][K] bf16 rows gathered via perm; Wt[4 local experts][N][K] bf16.
// EPI 0 (ffn1): Hout = bf16(acc + bias[e][n])
// EPI 1 (ffn2): Yout = (acc + bias[e][n]) * rsc[e] + Xres[tok][n]  (fp32)
// ---------------------------------------------------------------------------
template<int EPI>
__global__ __launch_bounds__(256, 2) void gemm_moe_kernel(
    const u16* __restrict__ A, const u16* __restrict__ Wt,
    const float* __restrict__ bias, const float* __restrict__ rsc,
    const float* __restrict__ Xres,
    const int* __restrict__ perm, const int* __restrict__ offs,
    const int* __restrict__ counts,
    u16* __restrict__ Hout, float* __restrict__ Yout,
    int N, int K, int e_base) {
  const int ez = blockIdx.z, e = e_base + ez;
  const int ne = counts[e];
  const int tm = blockIdx.y;
  if (tm * 128 >= ne) return;
  __shared__ u16 As_[128*64], Bs_[128*64];   // 32 KB
  __shared__ int toks[128];
  const int tid = threadIdx.x;
  if (tid < 128) {
    const int idx = tm * 128 + tid;
    toks[tid] = perm[offs[e] + (idx < ne ? idx : 0)];
  }
  __syncthreads();
  const int lane = tid & 63, wave = tid >> 6;
  const int wm = (wave & 1) * 64, wn = (wave >> 1) * 64;
  const int mr = tid >> 3;
  const int ksrc = (tid & 7) ^ ((tid >> 3) & 7);
  size_t abase[4];
  #pragma unroll
  for (int p = 0; p < 4; ++p) abase[p] = (size_t)toks[p * 32 + mr] * K;
  const u16* We = Wt + (size_t)ez * N * K;
  const int col0 = blockIdx.x * 128;
  const floatx4 zero = {0.f, 0.f, 0.f, 0.f};
  floatx4 acc[4][4];
  #pragma unroll
  for (int i = 0; i < 4; ++i)
    #pragma unroll
    for (int j = 0; j < 4; ++j) acc[i][j] = zero;

  for (int k0 = 0; k0 < K; k0 += 64) {
    __syncthreads();
    #pragma unroll
    for (int p = 0; p < 4; ++p) {
      const size_t off = (size_t)(p * 256 + wave * 64) * 16;
      gload16(A + abase[p] + (k0 + ksrc * 8), (char*)As_ + off);
      gload16(We + (size_t)(col0 + p * 32 + mr) * K + (k0 + ksrc * 8), (char*)Bs_ + off);
    }
    __syncthreads();
    #pragma unroll
    for (int kk = 0; kk < 2; ++kk) {
      short8 a[4], b[4];
      #pragma unroll
      for (int i = 0; i < 4; ++i) {
        const int ml = wm + i * 16 + (lane & 15);
        const int cm = (kk * 4 + (lane >> 4)) ^ (ml & 7);
        a[i] = *(const short8*)&As_[ml * 64 + cm * 8];
        const int nl = wn + i * 16 + (lane & 15);
        const int cn = (kk * 4 + (lane >> 4)) ^ (nl & 7);
        b[i] = *(const short8*)&Bs_[nl * 64 + cn * 8];
      }
      #pragma unroll
      for (int i = 0; i < 4; ++i)
        #pragma unroll
        for (int j = 0; j < 4; ++j)
          acc[i][j] = __builtin_amdgcn_mfma_f32_16x16x32_bf16(a[i], b[j], acc[i][j], 0, 0, 0);
    }
  }
  const int cl = lane & 15, quad = lane >> 4;
  const float rse = (EPI == 1) ? rsc[e] : 0.f;
  #pragma unroll
  for (int i = 0; i < 4; ++i)
    #pragma unroll
    for (int j = 0; j < 4; ++j) {
      const int col = col0 + wn + j * 16 + cl;
      #pragma unroll
      for (int r = 0; r < 4; ++r) {
        const int rl = wm + i * 16 + quad * 4 + r;
        if (tm * 128 + rl < ne) {
          const int tok = toks[rl];
          const float v = acc[i][j][r] + bias[(size_t)e * N + col];
          if (EPI == 0) Hout[(size_t)tok * N + col] = f2bf(v);
          else          Yout[(size_t)tok * N + col] = v * rse + Xres[(size_t)tok * N + col];
        }
      }
    }
}

// ---------------------------------------------------------------------------
// Flash attention, fp32 (kept exact-ish: feeds the router-sensitive path).
// grid = (S/64, H, B), block = 256.
// ---------------------------------------------------------------------------
__global__ __launch_bounds__(256) void attn_kernel(
    const float* __restrict__ Q, const float* __restrict__ K,
    const float* __restrict__ V, const float* __restrict__ scale_w,
    float* __restrict__ O) {
  int qt = blockIdx.x, hh = blockIdx.y, b = blockIdx.z;
  __shared__ float Qs[64][65];
  __shared__ float KS[64][65];   // K-tile during QK^T, then P-tile
  __shared__ float Vs[64][65];
  __shared__ float m_s[64], l_s[64], alpha_s[64], scale_s[64], sw[64];
  int tid = threadIdx.x;
  int tx = tid & 15, ty = tid >> 4;
  const size_t baseq = ((size_t)b * 1024 + (size_t)qt * 64) * 1024 + hh * 64;
  #pragma unroll
  for (int p = 0; p < 16; ++p) {
    int idx = p * 256 + tid;
    int r = idx >> 6, c = idx & 63;
    Qs[r][c] = Q[baseq + (size_t)r * 1024 + c];
  }
  if (tid < 64) sw[tid] = scale_w[hh * 64 + tid];
  __syncthreads();
  if (tid < 64) {
    float dot = 0.f;
    #pragma unroll
    for (int d = 0; d < 64; ++d) dot += Qs[tid][d] * sw[d];
    scale_s[tid] = 2.f * sigmoidf_(dot);
    m_s[tid] = -1e30f;
    l_s[tid] = 0.f;
  }
  float o[4][4] = {};
  for (int kt = 0; kt < 16; ++kt) {
    __syncthreads();
    const size_t basek = ((size_t)b * 1024 + (size_t)kt * 64) * 1024 + hh * 64;
    #pragma unroll
    for (int p = 0; p < 16; ++p) {
      int idx = p * 256 + tid;
      int r = idx >> 6, c = idx & 63;
      KS[r][c] = K[basek + (size_t)r * 1024 + c];
      Vs[r][c] = V[basek + (size_t)r * 1024 + c];
    }
    __syncthreads();
    float s_acc[4][4] = {};
    for (int d = 0; d < 64; ++d) {
      float qv[4], kv[4];
      #pragma unroll
      for (int i = 0; i < 4; ++i) qv[i] = Qs[ty*4+i][d];
      #pragma unroll
      for (int j = 0; j < 4; ++j) kv[j] = KS[tx*4+j][d];
      #pragma unroll
      for (int i = 0; i < 4; ++i)
        #pragma unroll
        for (int j = 0; j < 4; ++j) s_acc[i][j] += qv[i] * kv[j];
    }
    __syncthreads();
    #pragma unroll
    for (int i = 0; i < 4; ++i) {
      float sc = scale_s[ty*4+i] * 0.125f;
      #pragma unroll
      for (int j = 0; j < 4; ++j) KS[ty*4+i][tx*4+j] = s_acc[i][j] * sc;
    }
    __syncthreads();
    if (tid < 64) {
      float mold = m_s[tid];
      float rmax = mold;
      #pragma unroll
      for (int j = 0; j < 64; ++j) rmax = fmaxf(rmax, KS[tid][j]);
      float alpha = expf(mold - rmax);
      float rsum = 0.f;
      #pragma unroll
      for (int j = 0; j < 64; ++j) {
        float pv = expf(KS[tid][j] - rmax);
        KS[tid][j] = pv;
        rsum += pv;
      }
      l_s[tid] = l_s[tid] * alpha + rsum;
      m_s[tid] = rmax;
      alpha_s[tid] = alpha;
    }
    __syncthreads();
    float ar[4];
    #pragma unroll
    for (int i = 0; i < 4; ++i) ar[i] = alpha_s[ty*4+i];
    #pragma unroll
    for (int i = 0; i < 4; ++i)
      #pragma unroll
      for (int j = 0; j < 4; ++j) o[i][j] *= ar[i];
    for (int kr = 0; kr < 64; ++kr) {
      float pv[4], vv[4];
      #pragma unroll
      for (int i = 0; i < 4; ++i) pv[i] = KS[ty*4+i][kr];
      #pragma unroll
      for (int j = 0; j < 4; ++j) vv[j] = Vs[kr][tx*4+j];
      #pragma unroll
      for (int i = 0; i < 4; ++i)
        #pragma unroll
        for (int j = 0; j < 4; ++j) o[i][j] += pv[i] * vv[j];
    }
  }
  __syncthreads();
  #pragma unroll
  for (int i = 0; i < 4; ++i) {
    int qr = ty*4 + i;
    float invl = 1.f / l_s[qr];
    size_t orow = ((size_t)b*1024 + (size_t)qt*64 + qr) * 1024 + hh*64 + tx*4;
    *(float4*)&O[orow] = make_float4(o[i][0]*invl, o[i][1]*invl, o[i][2]*invl, o[i][3]*invl);
  }
}

// ---------------------------------------------------------------------------
// x = LN(a + b) * g + beta  -> fp32 out (+ optional bf16 copy for MFMA input)
// ---------------------------------------------------------------------------
template<bool BF>
__global__ __launch_bounds__(256) void ln_add_kernel(
    const float* __restrict__ A, const float* __restrict__ Bp,
    const float* __restrict__ g, const float* __restrict__ beta,
    float* __restrict__ outf, u16* __restrict__ outh) {
  int t = blockIdx.x, tid = threadIdx.x;
  const float* a = A + (size_t)t * DMODEL;
  const float* b = Bp + (size_t)t * DMODEL;
  float v[4]; float s = 0.f;
  #pragma unroll
  for (int i = 0; i < 4; ++i) { int d = tid + i*256; v[i] = a[d] + b[d]; s += v[i]; }
  s = blockReduceSum256(s);
  float mean = s * (1.f/1024.f);
  float q = 0.f;
  #pragma unroll
  for (int i = 0; i < 4; ++i) { float df = v[i]-mean; q += df*df; }
  q = blockReduceSum256(q);
  float rstd = rsqrtf(q*(1.f/1024.f) + 1e-5f);
  #pragma unroll
  for (int i = 0; i < 4; ++i) {
    int d = tid + i*256;
    float val = (v[i]-mean)*rstd*g[d] + beta[d];
    outf[(size_t)t*DMODEL + d] = val;
    if (BF) outh[(size_t)t*DMODEL + d] = f2bf(val);
  }
}

// ---------------------------------------------------------------------------
// MoE router (fp32 x, identical numerics to round 1): e_sel = max idx of top-2
// ---------------------------------------------------------------------------
__global__ __launch_bounds__(256) void moe_gate_kernel(
    const float* __restrict__ X, const float* __restrict__ gw,
    const float* __restrict__ gb, int* __restrict__ e_sel) {
  int wave = threadIdx.x >> 6, lane = threadIdx.x & 63;
  int token = blockIdx.x * 4 + wave;
  const float* x = X + (size_t)token * DMODEL;
  float acc[NEXP] = {};
  for (int d = lane; d < DMODEL; d += 64) {
    float xv = x[d];
    const float* gr = gw + (size_t)d * NEXP;
    #pragma unroll
    for (int e = 0; e < NEXP; ++e) acc[e] += xv * gr[e];
  }
  #pragma unroll
  for (int e = 0; e < NEXP; ++e) {
    #pragma unroll
    for (int off = 32; off; off >>= 1) acc[e] += __shfl_down(acc[e], off);
  }
  if (lane == 0) {
    float lg[NEXP];
    #pragma unroll
    for (int e = 0; e < NEXP; ++e) lg[e] = acc[e] + gb[e];
    int i1 = 0;
    for (int e = 1; e < NEXP; ++e) if (lg[e] > lg[i1]) i1 = e;
    int i2 = -1;
    for (int e = 0; e < NEXP; ++e) {
      if (e == i1) continue;
      if (i2 < 0 || lg[e] > lg[i2]) i2 = e;
    }
    e_sel[token] = (i1 > i2) ? i1 : i2;
  }
}

__global__ __launch_bounds__(256) void moe_group_kernel(
    const int* __restrict__ e_sel, int* __restrict__ perm,
    int* __restrict__ g_offs, int* __restrict__ g_counts) {
  __shared__ int cnt[NEXP], offs[NEXP], cur[NEXP];
  int tid = threadIdx.x;
  if (tid < NEXP) cnt[tid] = 0;
  __syncthreads();
  for (int t = tid; t < TOK; t += 256) atomicAdd(&cnt[e_sel[t]], 1);
  __syncthreads();
  if (tid == 0) {
    int run = 0;
    for (int e = 0; e < NEXP; ++e) { offs[e] = run; cur[e] = run; run += cnt[e]; }
  }
  __syncthreads();
  if (tid < NEXP) { g_offs[tid] = offs[tid]; g_counts[tid] = cnt[tid]; }
  for (int t = tid; t < TOK; t += 256) {
    int pos = atomicAdd(&cur[e_sel[t]], 1);
    perm[pos] = t;
  }
}

// LN over DFF (per selected expert) + exact-erf GELU, in place on bf16 h.
__global__ __launch_bounds__(256) void moe_ln_gelu_kernel(
    u16* __restrict__ H, const float* __restrict__ ln_g,
    const float* __restrict__ ln_b, const int* __restrict__ e_sel) {
  int t = blockIdx.x, tid = threadIdx.x;
  int e = e_sel[t];
  u16* h = H + (size_t)t * DFFN;
  float v[16]; float s = 0.f;
  #pragma unroll
  for (int i = 0; i < 16; ++i) { v[i] = bf2f(h[tid + i*256]); s += v[i]; }
  s = blockReduceSum256(s);
  float mean = s * (1.f/4096.f);
  float q = 0.f;
  #pragma unroll
  for (int i = 0; i < 16; ++i) { float df = v[i]-mean; q += df*df; }
  q = blockReduceSum256(q);
  float rstd = rsqrtf(q*(1.f/4096.f) + 1e-5f);
  const float* gg = ln_g + (size_t)e * DFFN;
  const float* bb = ln_b + (size_t)e * DFFN;
  #pragma unroll
  for (int i = 0; i < 16; ++i) {
    int d = tid + i*256;
    float x = (v[i]-mean)*rstd*gg[d] + bb[d];
    h[d] = f2bf(0.5f * x * (1.f + erff(x * 0.7071067811865475f)));
  }
}

// ---------------------------------------------------------------------------
extern "C" void kernel_launch(void* const* d_in, const int* in_sizes, int n_in,
                              void* d_out, int out_size, void* d_ws, size_t ws_size,
                              hipStream_t stream) {
  (void)in_sizes; (void)n_in; (void)out_size; (void)ws_size;
  const float* src    = (const float*)d_in[0];
  const float* qw     = (const float*)d_in[1];
  const float* kw     = (const float*)d_in[2];
  const float* vw     = (const float*)d_in[3];
  const float* ow     = (const float*)d_in[4];
  const float* gate_w = (const float*)d_in[5];
  const float* gate_b = (const float*)d_in[6];
  const float* scale_w= (const float*)d_in[7];
  const float* n1_g   = (const float*)d_in[8];
  const float* n1_b   = (const float*)d_in[9];
  const float* n2_g   = (const float*)d_in[10];
  const float* n2_b   = (const float*)d_in[11];
  const float* mgw    = (const float*)d_in[12];
  const float* mgb    = (const float*)d_in[13];
  const float* w1     = (const float*)d_in[14];
  const float* b1     = (const float*)d_in[15];
  const float* ln_g   = (const float*)d_in[16];
  const float* ln_b   = (const float*)d_in[17];
  const float* w2     = (const float*)d_in[18];
  const float* b2     = (const float*)d_in[19];
  const float* rs     = (const float*)d_in[20];

  char* ws = (char*)d_ws;
  const size_t MB = 1024 * 1024;
  // phase-1 buffers (all dead before WtA phase overwrites 0..32 MB)
  u16*   src_hi = (u16*)(ws + 0*MB);
  u16*   src_lo = (u16*)(ws + 4*MB);
  u16*   wt_hi  = (u16*)(ws + 8*MB);
  u16*   wt_lo  = (u16*)(ws + 10*MB);
  float* q      = (float*)(ws + 12*MB);
  float* k      = (float*)(ws + 20*MB);
  float* v      = (float*)(ws + 28*MB);
  float* ao     = (float*)(ws + 36*MB);
  u16*   ao_hi  = (u16*)(ws + 12*MB);   // reuse q
  u16*   ao_lo  = (u16*)(ws + 16*MB);
  u16*   gb_hi  = (u16*)(ws + 20*MB);   // reuse k
  u16*   gb_lo  = (u16*)(ws + 24*MB);
  float* proj   = (float*)(ws + 28*MB); // reuse v
  // persistent phase-2 buffers
  float* x      = (float*)(ws + 44*MB);
  u16*   x_hi   = (u16*)(ws + 52*MB);
  u16*   h      = (u16*)(ws + 56*MB);   // 16 MB bf16 [TOK][DFFN]
  float* y      = (float*)(ws + 72*MB);
  u16*   WtA    = (u16*)(ws + 0*MB);    // 32 MB: 4 experts' transposed weights
  int*   e_sel  = (int*)(ws + 80*MB);
  int*   perm   = e_sel + TOK;
  int*   offs   = perm + TOK;
  int*   cnts   = offs + NEXP;

  dim3 blk(256);
  split_kernel<<<2048, blk, 0, stream>>>(src, src_hi, src_lo);

  // QKV projections (split-bf16 MFMA; fp32-accurate for router safety)
  wt_conv_kernel<true><<<dim3(32,32,1), blk, 0, stream>>>(qw, wt_hi, wt_lo, DMODEL, DMODEL);
  gemm_split_kernel<0><<<dim3(8,16), blk, 0, stream>>>(src_hi, src_lo, wt_hi, wt_lo,
      nullptr, nullptr, q, nullptr, nullptr, TOK, DMODEL, DMODEL);
  wt_conv_kernel<true><<<dim3(32,32,1), blk, 0, stream>>>(kw, wt_hi, wt_lo, DMODEL, DMODEL);
  gemm_split_kernel<0><<<dim3(8,16), blk, 0, stream>>>(src_hi, src_lo, wt_hi, wt_lo,
      nullptr, nullptr, k, nullptr, nullptr, TOK, DMODEL, DMODEL);
  wt_conv_kernel<true><<<dim3(32,32,1), blk, 0, stream>>>(vw, wt_hi, wt_lo, DMODEL, DMODEL);
  gemm_split_kernel<0><<<dim3(8,16), blk, 0, stream>>>(src_hi, src_lo, wt_hi, wt_lo,
      nullptr, nullptr, v, nullptr, nullptr, TOK, DMODEL, DMODEL);

  // flash attention (fp32) with dynamic scale gate
  attn_kernel<<<dim3(16, NHEAD, 2), blk, 0, stream>>>(q, k, v, scale_w, ao);

  // gate = sigmoid(ao @ gate_w + gate_b); gbuf = ao * gate  (split output)
  split_kernel<<<2048, blk, 0, stream>>>(ao, ao_hi, ao_lo);
  wt_conv_kernel<true><<<dim3(32,32,1), blk, 0, stream>>>(gate_w, wt_hi, wt_lo, DMODEL, DMODEL);
  gemm_split_kernel<1><<<dim3(8,16), blk, 0, stream>>>(ao_hi, ao_lo, wt_hi, wt_lo,
      gate_b, ao, nullptr, gb_hi, gb_lo, TOK, DMODEL, DMODEL);
  // proj = gbuf @ ow
  wt_conv_kernel<true><<<dim3(32,32,1), blk, 0, stream>>>(ow, wt_hi, wt_lo, DMODEL, DMODEL);
  gemm_split_kernel<0><<<dim3(8,16), blk, 0, stream>>>(gb_hi, gb_lo, wt_hi, wt_lo,
      nullptr, nullptr, proj, nullptr, nullptr, TOK, DMODEL, DMODEL);

  // x = LN(src + proj); bf16 copy for MoE A-side
  ln_add_kernel<true><<<TOK, blk, 0, stream>>>(src, proj, n1_g, n1_b, x, x_hi);

  // router (fp32) + grouping
  moe_gate_kernel<<<TOK/4, blk, 0, stream>>>(x, mgw, mgb, e_sel);
  moe_group_kernel<<<1, blk, 0, stream>>>(e_sel, perm, offs, cnts);

  // FFN1 in two expert-chunks (WtA = 32 MB holds 4 experts)
  for (int c = 0; c < 2; ++c) {
    wt_conv_kernel<false><<<dim3(DFFN/32, DMODEL/32, 4), blk, 0, stream>>>(
        w1 + (size_t)c*4*DMODEL*DFFN, WtA, nullptr, DMODEL, DFFN);
    gemm_moe_kernel<0><<<dim3(DFFN/128, 16, 4), blk, 0, stream>>>(
        x_hi, WtA, b1, nullptr, nullptr, perm, offs, cnts, h, nullptr, DFFN, DMODEL, c*4);
  }
  moe_ln_gelu_kernel<<<TOK, blk, 0, stream>>>(h, ln_g, ln_b, e_sel);
  // FFN2 in two expert-chunks
  for (int c = 0; c < 2; ++c) {
    wt_conv_kernel<false><<<dim3(DMODEL/32, DFFN/32, 4), blk, 0, stream>>>(
        w2 + (size_t)c*4*DFFN*DMODEL, WtA, nullptr, DFFN, DMODEL);
    gemm_moe_kernel<1><<<dim3(DMODEL/128, 16, 4), blk, 0, stream>>>(
        h, WtA, b2, rs, x, perm, offs, cnts, nullptr, y, DMODEL, DFFN, c*4);
  }
  // out = LN(x + y)
  ln_add_kernel<false><<<TOK, blk, 0, stream>>>(x, y, n2_g, n2_b, (float*)d_out, nullptr);
}

// Round 3
// 808.470 us; speedup vs baseline: 2.1139x; 1.2657x over previous
//
#include <hip/hip_runtime.h>
#include <math.h>

// Problem constants (fixed by the reference)
#define TOK    2048      // B*S
#define DMODEL 1024
#define NHEAD  16
#define HDIM   64
#define NEXP   8
#define DFFN   4096

typedef unsigned short u16;
typedef __attribute__((ext_vector_type(8))) short short8;   // 8 bf16 (4 VGPRs)
typedef __attribute__((ext_vector_type(4))) float floatx4;  // MFMA C/D

__device__ __forceinline__ float sigmoidf_(float x) { return 1.f / (1.f + expf(-x)); }

__device__ __forceinline__ u16 f2bf(float f) {               // RNE fp32->bf16
  union { float f; unsigned u; } v; v.f = f;
  unsigned r = v.u + 0x7FFFu + ((v.u >> 16) & 1u);
  return (u16)(r >> 16);
}
__device__ __forceinline__ float bf2f(u16 h) {
  union { unsigned u; float f; } v; v.u = ((unsigned)h) << 16; return v.f;
}

// async global->LDS, 16B per lane; LDS dest = wave-uniform base + lane*16
__device__ __forceinline__ void gload16(const void* g, void* l) {
  __builtin_amdgcn_global_load_lds((const __attribute__((address_space(1))) void*)g,
                                   (__attribute__((address_space(3))) void*)l, 16, 0, 0);
}

// block = 256 threads (4 waves). Broadcast result to all threads.
__device__ __forceinline__ float blockReduceSum256(float val) {
  __shared__ float ws_[4];
  #pragma unroll
  for (int off = 32; off; off >>= 1) val += __shfl_down(val, off);
  int lane = threadIdx.x & 63, w = threadIdx.x >> 6;
  if (lane == 0) ws_[w] = val;
  __syncthreads();
  float r = ws_[0] + ws_[1] + ws_[2] + ws_[3];
  __syncthreads();
  return r;
}

// ---------------------------------------------------------------------------
// fp32 -> (hi, lo) bf16 split, elementwise. grid = n/1024, 4 floats/thread.
// ---------------------------------------------------------------------------
__global__ __launch_bounds__(256) void split_kernel(
    const float* __restrict__ X, u16* __restrict__ Hi, u16* __restrict__ Lo) {
  const int i = blockIdx.x * 256 + threadIdx.x;
  const float4 v = ((const float4*)X)[i];
  const float f[4] = {v.x, v.y, v.z, v.w};
  union { u16 s[4]; uint2 u; } h, l;
  #pragma unroll
  for (int j = 0; j < 4; ++j) {
    h.s[j] = f2bf(f[j]);
    l.s[j] = f2bf(f[j] - bf2f(h.s[j]));
  }
  ((uint2*)Hi)[i] = h.u;
  ((uint2*)Lo)[i] = l.u;
}

// ---------------------------------------------------------------------------
// Weight convert+transpose: W[K][N] fp32 -> Wt_hi[N][K] bf16 (+ optional lo).
// blockIdx.z = batch (expert); strides K*N. 32x32 LDS tile.
// ---------------------------------------------------------------------------
template<bool LO>
__global__ __launch_bounds__(256) void wt_conv_kernel(
    const float* __restrict__ W, u16* __restrict__ Whi, u16* __restrict__ Wlo,
    int K, int N) {
  const size_t z = blockIdx.z;
  W   += z * (size_t)K * N;
  Whi += z * (size_t)K * N;
  if (LO) Wlo += z * (size_t)K * N;
  __shared__ float tile[32][33];
  const int n0 = blockIdx.x * 32, k0 = blockIdx.y * 32;
  const int r = threadIdx.x >> 3, c4 = (threadIdx.x & 7) * 4;
  const float4 v = *(const float4*)&W[(size_t)(k0 + r) * N + n0 + c4];
  tile[r][c4+0] = v.x; tile[r][c4+1] = v.y; tile[r][c4+2] = v.z; tile[r][c4+3] = v.w;
  __syncthreads();
  union { u16 s[4]; uint2 u; } h, l;
  #pragma unroll
  for (int j = 0; j < 4; ++j) {
    const float f = tile[c4 + j][r];
    h.s[j] = f2bf(f);
    if (LO) l.s[j] = f2bf(f - bf2f(h.s[j]));
  }
  *(uint2*)&Whi[(size_t)(n0 + r) * K + k0 + c4] = h.u;
  if (LO) *(uint2*)&Wlo[(size_t)(n0 + r) * K + k0 + c4] = l.u;
}

// ---------------------------------------------------------------------------
// Split-precision bf16 MFMA GEMM: C[M,N] = A[M,K] @ W[K,N], where
// A is given as (Ahi,Alo) bf16 [M][K] and W as transposed (Whi,Wlo) bf16 [N][K].
// acc += Ah*Wh + Al*Wh + Ah*Wl  (error ~2^-18, protects MoE routing).
// 128x128 tile, BK=64, 4 waves (2x2 of 64x64), 16x16x32 MFMA.
// EPI 0: Cf = acc (fp32).
// EPI 1: g = sigmoid(acc+bias[n])*mul[m,n] -> Chi/Clo split.
// EPI 2: Chi/Clo = split(acc)            (QKV path for MFMA attention).
// ---------------------------------------------------------------------------
template<int EPI>
__global__ __launch_bounds__(256, 2) void gemm_split_kernel(
    const u16* __restrict__ Ahi, const u16* __restrict__ Alo,
    const u16* __restrict__ Whi, const u16* __restrict__ Wlo,
    const float* __restrict__ bias, const float* __restrict__ mul,
    float* __restrict__ Cf, u16* __restrict__ Chi, u16* __restrict__ Clo,
    int M, int N, int K) {
  __shared__ u16 Ah[128*64], Al[128*64], Bh[128*64], Bl[128*64];   // 64 KB
  const int tid = threadIdx.x;
  const int lane = tid & 63, wave = tid >> 6;
  const int row0 = blockIdx.y * 128, col0 = blockIdx.x * 128;
  const int wm = (wave & 1) * 64, wn = (wave >> 1) * 64;
  const int mr = tid >> 3;                       // staging row 0..31 (+p*32)
  const int ksrc = (tid & 7) ^ ((tid >> 3) & 7); // swizzled source k-chunk
  const floatx4 zero = {0.f, 0.f, 0.f, 0.f};
  floatx4 acc[4][4];
  #pragma unroll
  for (int i = 0; i < 4; ++i)
    #pragma unroll
    for (int j = 0; j < 4; ++j) acc[i][j] = zero;

  for (int k0 = 0; k0 < K; k0 += 64) {
    __syncthreads();
    #pragma unroll
    for (int p = 0; p < 4; ++p) {
      const int m = p * 32 + mr;
      const size_t ga = (size_t)(row0 + m) * K + (k0 + ksrc * 8);
      const size_t gb = (size_t)(col0 + m) * K + (k0 + ksrc * 8);
      const size_t off = (size_t)(p * 256 + wave * 64) * 16;   // bytes
      gload16(Ahi + ga, (char*)Ah + off);
      gload16(Alo + ga, (char*)Al + off);
      gload16(Whi + gb, (char*)Bh + off);
      gload16(Wlo + gb, (char*)Bl + off);
    }
    __syncthreads();
    #pragma unroll
    for (int kk = 0; kk < 2; ++kk) {
      short8 ah[4], al[4], bh[4], bl[4];
      #pragma unroll
      for (int i = 0; i < 4; ++i) {
        const int ml = wm + i * 16 + (lane & 15);
        const int cm = (kk * 4 + (lane >> 4)) ^ (ml & 7);
        ah[i] = *(const short8*)&Ah[ml * 64 + cm * 8];
        al[i] = *(const short8*)&Al[ml * 64 + cm * 8];
        const int nl = wn + i * 16 + (lane & 15);
        const int cn = (kk * 4 + (lane >> 4)) ^ (nl & 7);
        bh[i] = *(const short8*)&Bh[nl * 64 + cn * 8];
        bl[i] = *(const short8*)&Bl[nl * 64 + cn * 8];
      }
      #pragma unroll
      for (int i = 0; i < 4; ++i)
        #pragma unroll
        for (int j = 0; j < 4; ++j) {
          acc[i][j] = __builtin_amdgcn_mfma_f32_16x16x32_bf16(ah[i], bh[j], acc[i][j], 0, 0, 0);
          acc[i][j] = __builtin_amdgcn_mfma_f32_16x16x32_bf16(al[i], bh[j], acc[i][j], 0, 0, 0);
          acc[i][j] = __builtin_amdgcn_mfma_f32_16x16x32_bf16(ah[i], bl[j], acc[i][j], 0, 0, 0);
        }
    }
  }
  const int cl = lane & 15, quad = lane >> 4;
  #pragma unroll
  for (int i = 0; i < 4; ++i)
    #pragma unroll
    for (int j = 0; j < 4; ++j) {
      const int col = col0 + wn + j * 16 + cl;
      #pragma unroll
      for (int r = 0; r < 4; ++r) {
        const int row = row0 + wm + i * 16 + quad * 4 + r;
        const float v = acc[i][j][r];
        if (EPI == 0) {
          Cf[(size_t)row * N + col] = v;
        } else if (EPI == 1) {
          const float s = sigmoidf_(v + bias[col]);
          const float g = s * mul[(size_t)row * N + col];
          const u16 hh = f2bf(g);
          Chi[(size_t)row * N + col] = hh;
          Clo[(size_t)row * N + col] = f2bf(g - bf2f(hh));
        } else {
          const u16 hh = f2bf(v);
          Chi[(size_t)row * N + col] = hh;
          Clo[(size_t)row * N + col] = f2bf(v - bf2f(hh));
        }
      }
    }
}

// ---------------------------------------------------------------------------
// Grouped MoE GEMM, plain bf16 MFMA (post-routing; bf16 error is safe here).
// ---------------------------------------------------------------------------
template<int EPI>
__global__ __launch_bounds__(256, 2) void gemm_moe_kernel(
    const u16* __restrict__ A, const u16* __restrict__ Wt,
    const float* __restrict__ bias, const float* __restrict__ rsc,
    const float* __restrict__ Xres,
    const int* __restrict__ perm, const int* __restrict__ offs,
    const int* __restrict__ counts,
    u16* __restrict__ Hout, float* __restrict__ Yout,
    int N, int K, int e_base) {
  const int ez = blockIdx.z, e = e_base + ez;
  const int ne = counts[e];
  const int tm = blockIdx.y;
  if (tm * 128 >= ne) return;
  __shared__ u16 As_[128*64], Bs_[128*64];   // 32 KB
  __shared__ int toks[128];
  const int tid = threadIdx.x;
  if (tid < 128) {
    const int idx = tm * 128 + tid;
    toks[tid] = perm[offs[e] + (idx < ne ? idx : 0)];
  }
  __syncthreads();
  const int lane = tid & 63, wave = tid >> 6;
  const int wm = (wave & 1) * 64, wn = (wave >> 1) * 64;
  const int mr = tid >> 3;
  const int ksrc = (tid & 7) ^ ((tid >> 3) & 7);
  size_t abase[4];
  #pragma unroll
  for (int p = 0; p < 4; ++p) abase[p] = (size_t)toks[p * 32 + mr] * K;
  const u16* We = Wt + (size_t)ez * N * K;
  const int col0 = blockIdx.x * 128;
  const floatx4 zero = {0.f, 0.f, 0.f, 0.f};
  floatx4 acc[4][4];
  #pragma unroll
  for (int i = 0; i < 4; ++i)
    #pragma unroll
    for (int j = 0; j < 4; ++j) acc[i][j] = zero;

  for (int k0 = 0; k0 < K; k0 += 64) {
    __syncthreads();
    #pragma unroll
    for (int p = 0; p < 4; ++p) {
      const size_t off = (size_t)(p * 256 + wave * 64) * 16;
      gload16(A + abase[p] + (k0 + ksrc * 8), (char*)As_ + off);
      gload16(We + (size_t)(col0 + p * 32 + mr) * K + (k0 + ksrc * 8), (char*)Bs_ + off);
    }
    __syncthreads();
    #pragma unroll
    for (int kk = 0; kk < 2; ++kk) {
      short8 a[4], b[4];
      #pragma unroll
      for (int i = 0; i < 4; ++i) {
        const int ml = wm + i * 16 + (lane & 15);
        const int cm = (kk * 4 + (lane >> 4)) ^ (ml & 7);
        a[i] = *(const short8*)&As_[ml * 64 + cm * 8];
        const int nl = wn + i * 16 + (lane & 15);
        const int cn = (kk * 4 + (lane >> 4)) ^ (nl & 7);
        b[i] = *(const short8*)&Bs_[nl * 64 + cn * 8];
      }
      #pragma unroll
      for (int i = 0; i < 4; ++i)
        #pragma unroll
        for (int j = 0; j < 4; ++j)
          acc[i][j] = __builtin_amdgcn_mfma_f32_16x16x32_bf16(a[i], b[j], acc[i][j], 0, 0, 0);
    }
  }
  const int cl = lane & 15, quad = lane >> 4;
  const float rse = (EPI == 1) ? rsc[e] : 0.f;
  #pragma unroll
  for (int i = 0; i < 4; ++i)
    #pragma unroll
    for (int j = 0; j < 4; ++j) {
      const int col = col0 + wn + j * 16 + cl;
      #pragma unroll
      for (int r = 0; r < 4; ++r) {
        const int rl = wm + i * 16 + quad * 4 + r;
        if (tm * 128 + rl < ne) {
          const int tok = toks[rl];
          const float v = acc[i][j][r] + bias[(size_t)e * N + col];
          if (EPI == 0) Hout[(size_t)tok * N + col] = f2bf(v);
          else          Yout[(size_t)tok * N + col] = v * rse + Xres[(size_t)tok * N + col];
        }
      }
    }
}

// ---------------------------------------------------------------------------
// V transpose: qkv (v columns) -> Vt[bh][d][tok] hi/lo.  grid (16, 32).
// ---------------------------------------------------------------------------
__global__ __launch_bounds__(256) void vt_trans_kernel(
    const u16* __restrict__ QKh, const u16* __restrict__ QKl,
    u16* __restrict__ Vth, u16* __restrict__ Vtl) {
  const int tt = blockIdx.x;           // 64-token tile
  const int bh = blockIdx.y;           // b*16+h
  const int b = bh >> 4, h = bh & 15;
  __shared__ u16 th[64][72], tl[64][72];
  const int t = threadIdx.x;
  const int r = t >> 3, c8 = (t & 7) * 8;
  #pragma unroll
  for (int p = 0; p < 2; ++p) {
    const int tok = p * 32 + r;
    const size_t g = ((size_t)b * 1024 + tt * 64 + tok) * 3072 + 2048 + h * 64 + c8;
    *(uint4*)&th[tok][c8] = *(const uint4*)&QKh[g];
    *(uint4*)&tl[tok][c8] = *(const uint4*)&QKl[g];
  }
  __syncthreads();
  #pragma unroll
  for (int p = 0; p < 2; ++p) {
    const int d = p * 32 + r;
    union { u16 s[8]; uint4 u; } oh, ol;
    #pragma unroll
    for (int j = 0; j < 8; ++j) { oh.s[j] = th[c8 + j][d]; ol.s[j] = tl[c8 + j][d]; }
    const size_t g = ((size_t)bh * 64 + d) * 1024 + tt * 64 + c8;
    *(uint4*)&Vth[g] = oh.u;
    *(uint4*)&Vtl[g] = ol.u;
  }
}

// ---------------------------------------------------------------------------
// MFMA flash attention, split-bf16 (error ~1e-5: protects router decisions).
// grid = (S/64, H, B), block = 256 (4 waves; wave w owns q-rows w*16..w*16+15).
// Q/K from qkv hi/lo [tok][3072] (q at col 0, k at col 1024); V from Vt.
// Softmax fully in registers (shfl_xor row reductions in C-layout).
// P round-trips through per-wave LDS (stride-72 -> <=2-way bank aliasing).
// ---------------------------------------------------------------------------
__global__ __launch_bounds__(256, 2) void attn_mfma_kernel(
    const u16* __restrict__ QKh, const u16* __restrict__ QKl,
    const u16* __restrict__ Vth, const u16* __restrict__ Vtl,
    const float* __restrict__ scale_w,
    float* __restrict__ AOf, u16* __restrict__ AOh, u16* __restrict__ AOl) {
  const int qt = blockIdx.x, h = blockIdx.y, b = blockIdx.z;
  __shared__ u16 Kh[64*64], Kl[64*64], Vh[64*64], Vl[64*64];   // 32 KB
  __shared__ u16 Ph[4][16*72], Pl[4][16*72];                   // 18.4 KB
  const int tid = threadIdx.x, lane = tid & 63, wave = tid >> 6;
  const int i15 = lane & 15, quad = lane >> 4;
  const floatx4 zero = {0.f, 0.f, 0.f, 0.f};

  // Q A-fragments (rows = wave*16 + i15)
  short8 qh[2], ql[2];
  const size_t qrow = ((size_t)b * 1024 + qt * 64 + wave * 16 + i15) * 3072 + h * 64;
  #pragma unroll
  for (int kk = 0; kk < 2; ++kk) {
    qh[kk] = *(const short8*)&QKh[qrow + kk * 32 + quad * 8];
    ql[kk] = *(const short8*)&QKl[qrow + kk * 32 + quad * 8];
  }
  // dynamic scale gate: dot(Q_row, scale_w[h]) -> 2*sigmoid, folded with 1/sqrt(64)
  float dot = 0.f;
  #pragma unroll
  for (int kk = 0; kk < 2; ++kk)
    #pragma unroll
    for (int j = 0; j < 8; ++j) {
      const float sw = scale_w[h * 64 + kk * 32 + quad * 8 + j];
      dot += (bf2f((u16)qh[kk][j]) + bf2f((u16)ql[kk][j])) * sw;
    }
  dot += __shfl_xor(dot, 16);
  dot += __shfl_xor(dot, 32);
  const float g = 2.f * sigmoidf_(dot) * 0.125f;   // all lanes hold row i15's value
  float stot[4];
  #pragma unroll
  for (int r = 0; r < 4; ++r) stot[r] = __shfl(g, (lane >> 4) * 4 + r);

  float m_r[4], l_r[4];
  floatx4 Of[4];
  #pragma unroll
  for (int r = 0; r < 4; ++r) { m_r[r] = -1e30f; l_r[r] = 0.f; }
  #pragma unroll
  for (int f = 0; f < 4; ++f) Of[f] = zero;
  u16* PhW = Ph[wave];
  u16* PlW = Pl[wave];

  const int sr = tid >> 3, sc = ((tid & 7) ^ ((tid >> 3) & 7)) * 8;
  for (int kt = 0; kt < 16; ++kt) {
    __syncthreads();
    #pragma unroll
    for (int p = 0; p < 2; ++p) {
      const int row = p * 32 + sr;
      const size_t off = (size_t)(p * 256 + wave * 64) * 16;
      const size_t kg = ((size_t)b * 1024 + kt * 64 + row) * 3072 + 1024 + h * 64 + sc;
      gload16(QKh + kg, (char*)Kh + off);
      gload16(QKl + kg, (char*)Kl + off);
      const size_t vg = ((size_t)(b * 16 + h) * 64 + row) * 1024 + kt * 64 + sc;
      gload16(Vth + vg, (char*)Vh + off);
      gload16(Vtl + vg, (char*)Vl + off);
    }
    __syncthreads();
    // S = Q K^T (split)
    float pm[4][4];   // [jn][r]
    #pragma unroll
    for (int jn = 0; jn < 4; ++jn) {
      floatx4 a = zero;
      #pragma unroll
      for (int kk = 0; kk < 2; ++kk) {
        const int n = jn * 16 + i15;
        const int ch = ((kk * 4 + quad) ^ (n & 7)) * 8;
        const short8 bh = *(const short8*)&Kh[n * 64 + ch];
        const short8 bl = *(const short8*)&Kl[n * 64 + ch];
        a = __builtin_amdgcn_mfma_f32_16x16x32_bf16(qh[kk], bh, a, 0, 0, 0);
        a = __builtin_amdgcn_mfma_f32_16x16x32_bf16(ql[kk], bh, a, 0, 0, 0);
        a = __builtin_amdgcn_mfma_f32_16x16x32_bf16(qh[kk], bl, a, 0, 0, 0);
      }
      #pragma unroll
      for (int r = 0; r < 4; ++r) pm[jn][r] = a[r] * stot[r];
    }
    // online softmax, in registers
    float alpha[4];
    #pragma unroll
    for (int r = 0; r < 4; ++r) {
      float mx = fmaxf(fmaxf(pm[0][r], pm[1][r]), fmaxf(pm[2][r], pm[3][r]));
      mx = fmaxf(mx, __shfl_xor(mx, 1));
      mx = fmaxf(mx, __shfl_xor(mx, 2));
      mx = fmaxf(mx, __shfl_xor(mx, 4));
      mx = fmaxf(mx, __shfl_xor(mx, 8));
      const float mn = fmaxf(m_r[r], mx);
      alpha[r] = expf(m_r[r] - mn);
      m_r[r] = mn;
      float rs = 0.f;
      #pragma unroll
      for (int jn = 0; jn < 4; ++jn) { pm[jn][r] = expf(pm[jn][r] - mn); rs += pm[jn][r]; }
      rs += __shfl_xor(rs, 1);
      rs += __shfl_xor(rs, 2);
      rs += __shfl_xor(rs, 4);
      rs += __shfl_xor(rs, 8);
      l_r[r] = l_r[r] * alpha[r] + rs;
    }
    #pragma unroll
    for (int f = 0; f < 4; ++f)
      #pragma unroll
      for (int r = 0; r < 4; ++r) Of[f][r] *= alpha[r];
    // P -> per-wave LDS (hi/lo split)
    #pragma unroll
    for (int jn = 0; jn < 4; ++jn)
      #pragma unroll
      for (int r = 0; r < 4; ++r) {
        const int a = (quad * 4 + r) * 72 + jn * 16 + i15;
        const u16 hh = f2bf(pm[jn][r]);
        PhW[a] = hh;
        PlW[a] = f2bf(pm[jn][r] - bf2f(hh));
      }
    // O += P V (split); per-wave private P, no barrier needed
    #pragma unroll
    for (int kk = 0; kk < 2; ++kk) {
      const short8 pah = *(const short8*)&PhW[i15 * 72 + kk * 32 + quad * 8];
      const short8 pal = *(const short8*)&PlW[i15 * 72 + kk * 32 + quad * 8];
      #pragma unroll
      for (int f = 0; f < 4; ++f) {
        const int d = f * 16 + i15;
        const int ch = ((kk * 4 + quad) ^ (d & 7)) * 8;
        const short8 vbh = *(const short8*)&Vh[d * 64 + ch];
        const short8 vbl = *(const short8*)&Vl[d * 64 + ch];
        Of[f] = __builtin_amdgcn_mfma_f32_16x16x32_bf16(pah, vbh, Of[f], 0, 0, 0);
        Of[f] = __builtin_amdgcn_mfma_f32_16x16x32_bf16(pal, vbh, Of[f], 0, 0, 0);
        Of[f] = __builtin_amdgcn_mfma_f32_16x16x32_bf16(pah, vbl, Of[f], 0, 0, 0);
      }
    }
  }
  // epilogue: O/l -> ao fp32 + hi/lo split
  float inv[4];
  #pragma unroll
  for (int r = 0; r < 4; ++r) inv[r] = 1.f / l_r[r];
  #pragma unroll
  for (int f = 0; f < 4; ++f)
    #pragma unroll
    for (int r = 0; r < 4; ++r) {
      const size_t row = (size_t)b * 1024 + qt * 64 + wave * 16 + quad * 4 + r;
      const int col = h * 64 + f * 16 + i15;
      const float val = Of[f][r] * inv[r];
      AOf[row * 1024 + col] = val;
      const u16 hh = f2bf(val);
      AOh[row * 1024 + col] = hh;
      AOl[row * 1024 + col] = f2bf(val - bf2f(hh));
    }
}

// ---------------------------------------------------------------------------
// x = LN(a + b) * g + beta  -> fp32 out (+ optional bf16 copy for MFMA input)
// ---------------------------------------------------------------------------
template<bool BF>
__global__ __launch_bounds__(256) void ln_add_kernel(
    const float* __restrict__ A, const float* __restrict__ Bp,
    const float* __restrict__ g, const float* __restrict__ beta,
    float* __restrict__ outf, u16* __restrict__ outh) {
  int t = blockIdx.x, tid = threadIdx.x;
  const float* a = A + (size_t)t * DMODEL;
  const float* b = Bp + (size_t)t * DMODEL;
  float v[4]; float s = 0.f;
  #pragma unroll
  for (int i = 0; i < 4; ++i) { int d = tid + i*256; v[i] = a[d] + b[d]; s += v[i]; }
  s = blockReduceSum256(s);
  float mean = s * (1.f/1024.f);
  float q = 0.f;
  #pragma unroll
  for (int i = 0; i < 4; ++i) { float df = v[i]-mean; q += df*df; }
  q = blockReduceSum256(q);
  float rstd = rsqrtf(q*(1.f/1024.f) + 1e-5f);
  #pragma unroll
  for (int i = 0; i < 4; ++i) {
    int d = tid + i*256;
    float val = (v[i]-mean)*rstd*g[d] + beta[d];
    outf[(size_t)t*DMODEL + d] = val;
    if (BF) outh[(size_t)t*DMODEL + d] = f2bf(val);
  }
}

// ---------------------------------------------------------------------------
// MoE router (fp32): e_sel = max index of top-2 logits.
// ---------------------------------------------------------------------------
__global__ __launch_bounds__(256) void moe_gate_kernel(
    const float* __restrict__ X, const float* __restrict__ gw,
    const float* __restrict__ gb, int* __restrict__ e_sel) {
  int wave = threadIdx.x >> 6, lane = threadIdx.x & 63;
  int token = blockIdx.x * 4 + wave;
  const float* x = X + (size_t)token * DMODEL;
  float acc[NEXP] = {};
  for (int d = lane; d < DMODEL; d += 64) {
    float xv = x[d];
    const float* gr = gw + (size_t)d * NEXP;
    #pragma unroll
    for (int e = 0; e < NEXP; ++e) acc[e] += xv * gr[e];
  }
  #pragma unroll
  for (int e = 0; e < NEXP; ++e) {
    #pragma unroll
    for (int off = 32; off; off >>= 1) acc[e] += __shfl_down(acc[e], off);
  }
  if (lane == 0) {
    float lg[NEXP];
    #pragma unroll
    for (int e = 0; e < NEXP; ++e) lg[e] = acc[e] + gb[e];
    int i1 = 0;
    for (int e = 1; e < NEXP; ++e) if (lg[e] > lg[i1]) i1 = e;
    int i2 = -1;
    for (int e = 0; e < NEXP; ++e) {
      if (e == i1) continue;
      if (i2 < 0 || lg[e] > lg[i2]) i2 = e;
    }
    e_sel[token] = (i1 > i2) ? i1 : i2;
  }
}

__global__ __launch_bounds__(256) void moe_group_kernel(
    const int* __restrict__ e_sel, int* __restrict__ perm,
    int* __restrict__ g_offs, int* __restrict__ g_counts) {
  __shared__ int cnt[NEXP], offs[NEXP], cur[NEXP];
  int tid = threadIdx.x;
  if (tid < NEXP) cnt[tid] = 0;
  __syncthreads();
  for (int t = tid; t < TOK; t += 256) atomicAdd(&cnt[e_sel[t]], 1);
  __syncthreads();
  if (tid == 0) {
    int run = 0;
    for (int e = 0; e < NEXP; ++e) { offs[e] = run; cur[e] = run; run += cnt[e]; }
  }
  __syncthreads();
  if (tid < NEXP) { g_offs[tid] = offs[tid]; g_counts[tid] = cnt[tid]; }
  for (int t = tid; t < TOK; t += 256) {
    int pos = atomicAdd(&cur[e_sel[t]], 1);
    perm[pos] = t;
  }
}

// LN over DFF (per selected expert) + exact-erf GELU, in place on bf16 h.
__global__ __launch_bounds__(256) void moe_ln_gelu_kernel(
    u16* __restrict__ H, const float* __restrict__ ln_g,
    const float* __restrict__ ln_b, const int* __restrict__ e_sel) {
  int t = blockIdx.x, tid = threadIdx.x;
  int e = e_sel[t];
  u16* h = H + (size_t)t * DFFN;
  float v[16]; float s = 0.f;
  #pragma unroll
  for (int i = 0; i < 16; ++i) { v[i] = bf2f(h[tid + i*256]); s += v[i]; }
  s = blockReduceSum256(s);
  float mean = s * (1.f/4096.f);
  float q = 0.f;
  #pragma unroll
  for (int i = 0; i < 16; ++i) { float df = v[i]-mean; q += df*df; }
  q = blockReduceSum256(q);
  float rstd = rsqrtf(q*(1.f/4096.f) + 1e-5f);
  const float* gg = ln_g + (size_t)e * DFFN;
  const float* bb = ln_b + (size_t)e * DFFN;
  #pragma unroll
  for (int i = 0; i < 16; ++i) {
    int d = tid + i*256;
    float x = (v[i]-mean)*rstd*gg[d] + bb[d];
    h[d] = f2bf(0.5f * x * (1.f + erff(x * 0.7071067811865475f)));
  }
}

// ---------------------------------------------------------------------------
extern "C" void kernel_launch(void* const* d_in, const int* in_sizes, int n_in,
                              void* d_out, int out_size, void* d_ws, size_t ws_size,
                              hipStream_t stream) {
  (void)in_sizes; (void)n_in; (void)out_size; (void)ws_size;
  const float* src    = (const float*)d_in[0];
  const float* qw     = (const float*)d_in[1];
  const float* kw     = (const float*)d_in[2];
  const float* vw     = (const float*)d_in[3];
  const float* ow     = (const float*)d_in[4];
  const float* gate_w = (const float*)d_in[5];
  const float* gate_b = (const float*)d_in[6];
  const float* scale_w= (const float*)d_in[7];
  const float* n1_g   = (const float*)d_in[8];
  const float* n1_b   = (const float*)d_in[9];
  const float* n2_g   = (const float*)d_in[10];
  const float* n2_b   = (const float*)d_in[11];
  const float* mgw    = (const float*)d_in[12];
  const float* mgb    = (const float*)d_in[13];
  const float* w1     = (const float*)d_in[14];
  const float* b1     = (const float*)d_in[15];
  const float* ln_g   = (const float*)d_in[16];
  const float* ln_b   = (const float*)d_in[17];
  const float* w2     = (const float*)d_in[18];
  const float* b2     = (const float*)d_in[19];
  const float* rs     = (const float*)d_in[20];

  char* ws = (char*)d_ws;
  const size_t MB = 1024 * 1024;
  // timeline-packed buffers (see comments for lifetime)
  u16*   qkv_hi = (u16*)(ws + 0*MB);    // 12 MB  [dead after attn]
  u16*   qkv_lo = (u16*)(ws + 12*MB);   // 12 MB
  u16*   Wt3_hi = (u16*)(ws + 24*MB);   // 6 MB   [QKV weights / reused per GEMM]
  u16*   Wt3_lo = (u16*)(ws + 30*MB);   // 6 MB
  u16*   Vt_hi  = (u16*)(ws + 36*MB);   // 4 MB   [dead after attn]
  u16*   Vt_lo  = (u16*)(ws + 40*MB);   // 4 MB
  u16*   src_hi = (u16*)(ws + 44*MB);   // 4 MB   [dead after QKV gemm]
  u16*   src_lo = (u16*)(ws + 48*MB);   // 4 MB
  float* ao     = (float*)(ws + 44*MB); // 8 MB   [written by attn, after src dead]
  u16*   ao_hi  = (u16*)(ws + 52*MB);   // 4 MB
  u16*   ao_lo  = (u16*)(ws + 56*MB);   // 4 MB
  u16*   gb_hi  = (u16*)(ws + 60*MB);   // 4 MB   [dead after ow gemm]
  u16*   gb_lo  = (u16*)(ws + 64*MB);   // 4 MB
  float* proj   = (float*)(ws + 0*MB);  // 8 MB   [qkv dead by then]
  float* x      = (float*)(ws + 8*MB);  // 8 MB   [persists]
  u16*   x_hi   = (u16*)(ws + 16*MB);   // 4 MB
  u16*   WtA    = (u16*)(ws + 24*MB);   // 32 MB  [MoE phase; Wt3/Vt/ao dead]
  u16*   h      = (u16*)(ws + 56*MB);   // 16 MB  [ao_lo/gb dead]
  float* y      = (float*)(ws + 72*MB); // 8 MB
  int*   e_sel  = (int*)(ws + 80*MB);
  int*   perm   = e_sel + TOK;
  int*   offs   = perm + TOK;
  int*   cnts   = offs + NEXP;

  dim3 blk(256);
  split_kernel<<<2048, blk, 0, stream>>>(src, src_hi, src_lo);

  // fused QKV: Wt3[3072][1024] <- qw|kw|vw; one 2048x3072x1024 split GEMM
  wt_conv_kernel<true><<<dim3(32,32,1), blk, 0, stream>>>(qw, Wt3_hi, Wt3_lo, DMODEL, DMODEL);
  wt_conv_kernel<true><<<dim3(32,32,1), blk, 0, stream>>>(kw, Wt3_hi + 1024*1024, Wt3_lo + 1024*1024, DMODEL, DMODEL);
  wt_conv_kernel<true><<<dim3(32,32,1), blk, 0, stream>>>(vw, Wt3_hi + 2048*1024, Wt3_lo + 2048*1024, DMODEL, DMODEL);
  gemm_split_kernel<2><<<dim3(24,16), blk, 0, stream>>>(src_hi, src_lo, Wt3_hi, Wt3_lo,
      nullptr, nullptr, nullptr, qkv_hi, qkv_lo, TOK, 3072, DMODEL);

  // V transpose + MFMA flash attention (split-bf16, dynamic scale gate)
  vt_trans_kernel<<<dim3(16,32), blk, 0, stream>>>(qkv_hi, qkv_lo, Vt_hi, Vt_lo);
  attn_mfma_kernel<<<dim3(16, NHEAD, 2), blk, 0, stream>>>(
      qkv_hi, qkv_lo, Vt_hi, Vt_lo, scale_w, ao, ao_hi, ao_lo);

  // gate = sigmoid(ao @ gate_w + gate_b); gbuf = ao * gate (split output)
  wt_conv_kernel<true><<<dim3(32,32,1), blk, 0, stream>>>(gate_w, Wt3_hi, Wt3_lo, DMODEL, DMODEL);
  gemm_split_kernel<1><<<dim3(8,16), blk, 0, stream>>>(ao_hi, ao_lo, Wt3_hi, Wt3_lo,
      gate_b, ao, nullptr, gb_hi, gb_lo, TOK, DMODEL, DMODEL);
  // proj = gbuf @ ow
  wt_conv_kernel<true><<<dim3(32,32,1), blk, 0, stream>>>(ow, Wt3_hi, Wt3_lo, DMODEL, DMODEL);
  gemm_split_kernel<0><<<dim3(8,16), blk, 0, stream>>>(gb_hi, gb_lo, Wt3_hi, Wt3_lo,
      nullptr, nullptr, proj, nullptr, nullptr, TOK, DMODEL, DMODEL);

  // x = LN(src + proj); bf16 copy for MoE A-side
  ln_add_kernel<true><<<TOK, blk, 0, stream>>>(src, proj, n1_g, n1_b, x, x_hi);

  // router (fp32) + grouping
  moe_gate_kernel<<<TOK/4, blk, 0, stream>>>(x, mgw, mgb, e_sel);
  moe_group_kernel<<<1, blk, 0, stream>>>(e_sel, perm, offs, cnts);

  // FFN1 in two expert-chunks (WtA = 32 MB holds 4 experts)
  for (int c = 0; c < 2; ++c) {
    wt_conv_kernel<false><<<dim3(DFFN/32, DMODEL/32, 4), blk, 0, stream>>>(
        w1 + (size_t)c*4*DMODEL*DFFN, WtA, nullptr, DMODEL, DFFN);
    gemm_moe_kernel<0><<<dim3(DFFN/128, 16, 4), blk, 0, stream>>>(
        x_hi, WtA, b1, nullptr, nullptr, perm, offs, cnts, h, nullptr, DFFN, DMODEL, c*4);
  }
  moe_ln_gelu_kernel<<<TOK, blk, 0, stream>>>(h, ln_g, ln_b, e_sel);
  // FFN2 in two expert-chunks
  for (int c = 0; c < 2; ++c) {
    wt_conv_kernel<false><<<dim3(DMODEL/32, DFFN/32, 4), blk, 0, stream>>>(
        w2 + (size_t)c*4*DFFN*DMODEL, WtA, nullptr, DFFN, DMODEL);
    gemm_moe_kernel<1><<<dim3(DMODEL/128, 16, 4), blk, 0, stream>>>(
        h, WtA, b2, rs, x, perm, offs, cnts, nullptr, y, DMODEL, DFFN, c*4);
  }
  // out = LN(x + y)
  ln_add_kernel<false><<<TOK, blk, 0, stream>>>(x, y, n2_g, n2_b, (float*)d_out, nullptr);
}

// Round 4
// 714.577 us; speedup vs baseline: 2.3917x; 1.1314x over previous
//
#include <hip/hip_runtime.h>
#include <math.h>

// Problem constants (fixed by the reference)
#define TOK    2048      // B*S
#define DMODEL 1024
#define NHEAD  16
#define HDIM   64
#define NEXP   8
#define DFFN   4096

typedef unsigned short u16;
typedef __attribute__((ext_vector_type(8))) short short8;   // 8 bf16 (4 VGPRs)
typedef __attribute__((ext_vector_type(4))) float floatx4;  // MFMA C/D

__device__ __forceinline__ float sigmoidf_(float x) { return 1.f / (1.f + expf(-x)); }

__device__ __forceinline__ u16 f2bf(float f) {               // RNE fp32->bf16
  union { float f; unsigned u; } v; v.f = f;
  unsigned r = v.u + 0x7FFFu + ((v.u >> 16) & 1u);
  return (u16)(r >> 16);
}
__device__ __forceinline__ float bf2f(u16 h) {
  union { unsigned u; float f; } v; v.u = ((unsigned)h) << 16; return v.f;
}

// async global->LDS, 16B per lane; LDS dest = wave-uniform base + lane*16
__device__ __forceinline__ void gload16(const void* g, void* l) {
  __builtin_amdgcn_global_load_lds((const __attribute__((address_space(1))) void*)g,
                                   (__attribute__((address_space(3))) void*)l, 16, 0, 0);
}

// block = 256 threads (4 waves). Broadcast result to all threads.
__device__ __forceinline__ float blockReduceSum256(float val) {
  __shared__ float ws_[4];
  #pragma unroll
  for (int off = 32; off; off >>= 1) val += __shfl_down(val, off);
  int lane = threadIdx.x & 63, w = threadIdx.x >> 6;
  if (lane == 0) ws_[w] = val;
  __syncthreads();
  float r = ws_[0] + ws_[1] + ws_[2] + ws_[3];
  __syncthreads();
  return r;
}

// ---------------------------------------------------------------------------
// fp32 -> (hi, lo) bf16 split, elementwise. grid = n/1024, 4 floats/thread.
// ---------------------------------------------------------------------------
__global__ __launch_bounds__(256) void split_kernel(
    const float* __restrict__ X, u16* __restrict__ Hi, u16* __restrict__ Lo) {
  const int i = blockIdx.x * 256 + threadIdx.x;
  const float4 v = ((const float4*)X)[i];
  const float f[4] = {v.x, v.y, v.z, v.w};
  union { u16 s[4]; uint2 u; } h, l;
  #pragma unroll
  for (int j = 0; j < 4; ++j) {
    h.s[j] = f2bf(f[j]);
    l.s[j] = f2bf(f[j] - bf2f(h.s[j]));
  }
  ((uint2*)Hi)[i] = h.u;
  ((uint2*)Lo)[i] = l.u;
}

// ---------------------------------------------------------------------------
// Weight convert+transpose: W[K][N] fp32 -> Wt_hi[N][K] bf16 (+ optional lo).
// blockIdx.z = batch (expert); strides K*N. 32x32 LDS tile.
// ---------------------------------------------------------------------------
template<bool LO>
__global__ __launch_bounds__(256) void wt_conv_kernel(
    const float* __restrict__ W, u16* __restrict__ Whi, u16* __restrict__ Wlo,
    int K, int N) {
  const size_t z = blockIdx.z;
  W   += z * (size_t)K * N;
  Whi += z * (size_t)K * N;
  if (LO) Wlo += z * (size_t)K * N;
  __shared__ float tile[32][33];
  const int n0 = blockIdx.x * 32, k0 = blockIdx.y * 32;
  const int r = threadIdx.x >> 3, c4 = (threadIdx.x & 7) * 4;
  const float4 v = *(const float4*)&W[(size_t)(k0 + r) * N + n0 + c4];
  tile[r][c4+0] = v.x; tile[r][c4+1] = v.y; tile[r][c4+2] = v.z; tile[r][c4+3] = v.w;
  __syncthreads();
  union { u16 s[4]; uint2 u; } h, l;
  #pragma unroll
  for (int j = 0; j < 4; ++j) {
    const float f = tile[c4 + j][r];
    h.s[j] = f2bf(f);
    if (LO) l.s[j] = f2bf(f - bf2f(h.s[j]));
  }
  *(uint2*)&Whi[(size_t)(n0 + r) * K + k0 + c4] = h.u;
  if (LO) *(uint2*)&Wlo[(size_t)(n0 + r) * K + k0 + c4] = l.u;
}

// ---------------------------------------------------------------------------
// Split-precision bf16 MFMA GEMM: C[M,N] = A[M,K] @ W[K,N].
// A as (Ahi,Alo) bf16 [M][K]; W transposed (Whi,Wlo) bf16 [N][K].
// acc += Ah*Wh + Al*Wh + Ah*Wl  (error ~2^-18, protects MoE routing).
// Tile 128(M)x64(N), BK=64, 4 waves as 2x2 (wave tile 64x32), 16x16x32 MFMA.
// LDS chunk-swizzle: chunk c of row m holds global k-chunk (c ^ (m&7)).
// EPI 0: Cf = acc (fp32).
// EPI 1: g = sigmoid(acc+bias[n])*mul[m,n] -> Chi/Clo split.
// EPI 2: Chi/Clo = split(acc)            (QKV path for MFMA attention).
// ---------------------------------------------------------------------------
template<int EPI>
__global__ __launch_bounds__(256, 3) void gemm_split_kernel(
    const u16* __restrict__ Ahi, const u16* __restrict__ Alo,
    const u16* __restrict__ Whi, const u16* __restrict__ Wlo,
    const float* __restrict__ bias, const float* __restrict__ mul,
    float* __restrict__ Cf, u16* __restrict__ Chi, u16* __restrict__ Clo,
    int M, int N, int K) {
  __shared__ u16 Ah[128*64], Al[128*64], Bh[64*64], Bl[64*64];   // 48 KB
  const int tid = threadIdx.x;
  const int lane = tid & 63, wave = tid >> 6;
  const int row0 = blockIdx.y * 128, col0 = blockIdx.x * 64;
  const int wm = (wave & 1) * 64, wn = (wave >> 1) * 32;
  const int mr = tid >> 3;                       // staging row 0..31 (+p*32)
  const int ksrc = (tid & 7) ^ ((tid >> 3) & 7); // swizzled source k-chunk
  const floatx4 zero = {0.f, 0.f, 0.f, 0.f};
  floatx4 acc[4][2];
  #pragma unroll
  for (int i = 0; i < 4; ++i)
    #pragma unroll
    for (int j = 0; j < 2; ++j) acc[i][j] = zero;

  for (int k0 = 0; k0 < K; k0 += 64) {
    __syncthreads();
    #pragma unroll
    for (int p = 0; p < 4; ++p) {               // A: 128 rows
      const size_t ga = (size_t)(row0 + p * 32 + mr) * K + (k0 + ksrc * 8);
      const size_t off = (size_t)(p * 256 + wave * 64) * 16;
      gload16(Ahi + ga, (char*)Ah + off);
      gload16(Alo + ga, (char*)Al + off);
    }
    #pragma unroll
    for (int p = 0; p < 2; ++p) {               // B: 64 rows
      const size_t gb = (size_t)(col0 + p * 32 + mr) * K + (k0 + ksrc * 8);
      const size_t off = (size_t)(p * 256 + wave * 64) * 16;
      gload16(Whi + gb, (char*)Bh + off);
      gload16(Wlo + gb, (char*)Bl + off);
    }
    __syncthreads();
    #pragma unroll
    for (int kk = 0; kk < 2; ++kk) {
      short8 ah[4], al[4], bh[2], bl[2];
      #pragma unroll
      for (int i = 0; i < 4; ++i) {
        const int ml = wm + i * 16 + (lane & 15);
        const int cm = (kk * 4 + (lane >> 4)) ^ (ml & 7);
        ah[i] = *(const short8*)&Ah[ml * 64 + cm * 8];
        al[i] = *(const short8*)&Al[ml * 64 + cm * 8];
      }
      #pragma unroll
      for (int j = 0; j < 2; ++j) {
        const int nl = wn + j * 16 + (lane & 15);
        const int cn = (kk * 4 + (lane >> 4)) ^ (nl & 7);
        bh[j] = *(const short8*)&Bh[nl * 64 + cn * 8];
        bl[j] = *(const short8*)&Bl[nl * 64 + cn * 8];
      }
      #pragma unroll
      for (int i = 0; i < 4; ++i)
        #pragma unroll
        for (int j = 0; j < 2; ++j) {
          acc[i][j] = __builtin_amdgcn_mfma_f32_16x16x32_bf16(ah[i], bh[j], acc[i][j], 0, 0, 0);
          acc[i][j] = __builtin_amdgcn_mfma_f32_16x16x32_bf16(al[i], bh[j], acc[i][j], 0, 0, 0);
          acc[i][j] = __builtin_amdgcn_mfma_f32_16x16x32_bf16(ah[i], bl[j], acc[i][j], 0, 0, 0);
        }
    }
  }
  const int cl = lane & 15, quad = lane >> 4;
  #pragma unroll
  for (int i = 0; i < 4; ++i)
    #pragma unroll
    for (int j = 0; j < 2; ++j) {
      const int col = col0 + wn + j * 16 + cl;
      #pragma unroll
      for (int r = 0; r < 4; ++r) {
        const int row = row0 + wm + i * 16 + quad * 4 + r;
        const float v = acc[i][j][r];
        if (EPI == 0) {
          Cf[(size_t)row * N + col] = v;
        } else if (EPI == 1) {
          const float s = sigmoidf_(v + bias[col]);
          const float g = s * mul[(size_t)row * N + col];
          const u16 hh = f2bf(g);
          Chi[(size_t)row * N + col] = hh;
          Clo[(size_t)row * N + col] = f2bf(g - bf2f(hh));
        } else {
          const u16 hh = f2bf(v);
          Chi[(size_t)row * N + col] = hh;
          Clo[(size_t)row * N + col] = f2bf(v - bf2f(hh));
        }
      }
    }
}

// ---------------------------------------------------------------------------
// Grouped MoE GEMM, plain bf16 MFMA. Tile 128(M)x64(N), 4 waves 2x2.
// EPI 0 (ffn1): z = local expert (4); full K. Hout = bf16(acc + bias[e][n]).
// EPI 1 (ffn2): z = ez + 4*ks (8): 2-way split-K; P[ks][tok*N+col] = acc fp32.
// ---------------------------------------------------------------------------
template<int EPI>
__global__ __launch_bounds__(256, 4) void gemm_moe_kernel(
    const u16* __restrict__ A, const u16* __restrict__ Wt,
    const float* __restrict__ bias,
    const int* __restrict__ perm, const int* __restrict__ offs,
    const int* __restrict__ counts,
    u16* __restrict__ Hout, float* __restrict__ P0, float* __restrict__ P1,
    int N, int K, int e_base) {
  const int z = blockIdx.z;
  const int ez = (EPI == 0) ? z : (z & 3);
  const int ks = (EPI == 0) ? 0 : (z >> 2);
  const int e = e_base + ez;
  const int ne = counts[e];
  const int tm = blockIdx.y;
  if (tm * 128 >= ne) return;
  const int kbeg = (EPI == 0) ? 0 : ks * (K >> 1);
  const int kend = (EPI == 0) ? K : kbeg + (K >> 1);
  __shared__ u16 As_[128*64], Bs_[64*64];   // 24 KB
  __shared__ int toks[128];
  const int tid = threadIdx.x;
  if (tid < 128) {
    const int idx = tm * 128 + tid;
    toks[tid] = perm[offs[e] + (idx < ne ? idx : 0)];
  }
  __syncthreads();
  const int lane = tid & 63, wave = tid >> 6;
  const int wm = (wave & 1) * 64, wn = (wave >> 1) * 32;
  const int mr = tid >> 3;
  const int ksrc = (tid & 7) ^ ((tid >> 3) & 7);
  size_t abase[4];
  #pragma unroll
  for (int p = 0; p < 4; ++p) abase[p] = (size_t)toks[p * 32 + mr] * K;
  const u16* We = Wt + (size_t)ez * N * K;
  const int col0 = blockIdx.x * 64;
  const floatx4 zero = {0.f, 0.f, 0.f, 0.f};
  floatx4 acc[4][2];
  #pragma unroll
  for (int i = 0; i < 4; ++i)
    #pragma unroll
    for (int j = 0; j < 2; ++j) acc[i][j] = zero;

  for (int k0 = kbeg; k0 < kend; k0 += 64) {
    __syncthreads();
    #pragma unroll
    for (int p = 0; p < 4; ++p) {
      const size_t off = (size_t)(p * 256 + wave * 64) * 16;
      gload16(A + abase[p] + (k0 + ksrc * 8), (char*)As_ + off);
    }
    #pragma unroll
    for (int p = 0; p < 2; ++p) {
      const size_t off = (size_t)(p * 256 + wave * 64) * 16;
      gload16(We + (size_t)(col0 + p * 32 + mr) * K + (k0 + ksrc * 8), (char*)Bs_ + off);
    }
    __syncthreads();
    #pragma unroll
    for (int kk = 0; kk < 2; ++kk) {
      short8 a[4], b[2];
      #pragma unroll
      for (int i = 0; i < 4; ++i) {
        const int ml = wm + i * 16 + (lane & 15);
        const int cm = (kk * 4 + (lane >> 4)) ^ (ml & 7);
        a[i] = *(const short8*)&As_[ml * 64 + cm * 8];
      }
      #pragma unroll
      for (int j = 0; j < 2; ++j) {
        const int nl = wn + j * 16 + (lane & 15);
        const int cn = (kk * 4 + (lane >> 4)) ^ (nl & 7);
        b[j] = *(const short8*)&Bs_[nl * 64 + cn * 8];
      }
      #pragma unroll
      for (int i = 0; i < 4; ++i)
        #pragma unroll
        for (int j = 0; j < 2; ++j)
          acc[i][j] = __builtin_amdgcn_mfma_f32_16x16x32_bf16(a[i], b[j], acc[i][j], 0, 0, 0);
    }
  }
  const int cl = lane & 15, quad = lane >> 4;
  float* Pp = (EPI == 1) ? (ks ? P1 : P0) : nullptr;
  #pragma unroll
  for (int i = 0; i < 4; ++i)
    #pragma unroll
    for (int j = 0; j < 2; ++j) {
      const int col = col0 + wn + j * 16 + cl;
      #pragma unroll
      for (int r = 0; r < 4; ++r) {
        const int rl = wm + i * 16 + quad * 4 + r;
        if (tm * 128 + rl < ne) {
          const int tok = toks[rl];
          if (EPI == 0)
            Hout[(size_t)tok * N + col] = f2bf(acc[i][j][r] + bias[(size_t)e * N + col]);
          else
            Pp[(size_t)tok * N + col] = acc[i][j][r];
        }
      }
    }
}

// ---------------------------------------------------------------------------
// V transpose: qkv (v columns) -> Vt[bh][d][tok] hi/lo.  grid (16, 32).
// ---------------------------------------------------------------------------
__global__ __launch_bounds__(256) void vt_trans_kernel(
    const u16* __restrict__ QKh, const u16* __restrict__ QKl,
    u16* __restrict__ Vth, u16* __restrict__ Vtl) {
  const int tt = blockIdx.x;           // 64-token tile
  const int bh = blockIdx.y;           // b*16+h
  const int b = bh >> 4, h = bh & 15;
  __shared__ u16 th[64][72], tl[64][72];
  const int t = threadIdx.x;
  const int r = t >> 3, c8 = (t & 7) * 8;
  #pragma unroll
  for (int p = 0; p < 2; ++p) {
    const int tok = p * 32 + r;
    const size_t g = ((size_t)b * 1024 + tt * 64 + tok) * 3072 + 2048 + h * 64 + c8;
    *(uint4*)&th[tok][c8] = *(const uint4*)&QKh[g];
    *(uint4*)&tl[tok][c8] = *(const uint4*)&QKl[g];
  }
  __syncthreads();
  #pragma unroll
  for (int p = 0; p < 2; ++p) {
    const int d = p * 32 + r;
    union { u16 s[8]; uint4 u; } oh, ol;
    #pragma unroll
    for (int j = 0; j < 8; ++j) { oh.s[j] = th[c8 + j][d]; ol.s[j] = tl[c8 + j][d]; }
    const size_t g = ((size_t)bh * 64 + d) * 1024 + tt * 64 + c8;
    *(uint4*)&Vth[g] = oh.u;
    *(uint4*)&Vtl[g] = ol.u;
  }
}

// ---------------------------------------------------------------------------
// MFMA flash attention, split-bf16 (error ~1e-5: protects router decisions).
// grid = (S/64, H, B), block = 256 (4 waves; wave w owns q-rows w*16..w*16+15).
// ---------------------------------------------------------------------------
__global__ __launch_bounds__(256, 2) void attn_mfma_kernel(
    const u16* __restrict__ QKh, const u16* __restrict__ QKl,
    const u16* __restrict__ Vth, const u16* __restrict__ Vtl,
    const float* __restrict__ scale_w,
    float* __restrict__ AOf, u16* __restrict__ AOh, u16* __restrict__ AOl) {
  const int qt = blockIdx.x, h = blockIdx.y, b = blockIdx.z;
  __shared__ u16 Kh[64*64], Kl[64*64], Vh[64*64], Vl[64*64];   // 32 KB
  __shared__ u16 Ph[4][16*72], Pl[4][16*72];                   // 18.4 KB
  const int tid = threadIdx.x, lane = tid & 63, wave = tid >> 6;
  const int i15 = lane & 15, quad = lane >> 4;
  const floatx4 zero = {0.f, 0.f, 0.f, 0.f};

  short8 qh[2], ql[2];
  const size_t qrow = ((size_t)b * 1024 + qt * 64 + wave * 16 + i15) * 3072 + h * 64;
  #pragma unroll
  for (int kk = 0; kk < 2; ++kk) {
    qh[kk] = *(const short8*)&QKh[qrow + kk * 32 + quad * 8];
    ql[kk] = *(const short8*)&QKl[qrow + kk * 32 + quad * 8];
  }
  float dot = 0.f;
  #pragma unroll
  for (int kk = 0; kk < 2; ++kk)
    #pragma unroll
    for (int j = 0; j < 8; ++j) {
      const float sw = scale_w[h * 64 + kk * 32 + quad * 8 + j];
      dot += (bf2f((u16)qh[kk][j]) + bf2f((u16)ql[kk][j])) * sw;
    }
  dot += __shfl_xor(dot, 16);
  dot += __shfl_xor(dot, 32);
  const float g = 2.f * sigmoidf_(dot) * 0.125f;
  float stot[4];
  #pragma unroll
  for (int r = 0; r < 4; ++r) stot[r] = __shfl(g, (lane >> 4) * 4 + r);

  float m_r[4], l_r[4];
  floatx4 Of[4];
  #pragma unroll
  for (int r = 0; r < 4; ++r) { m_r[r] = -1e30f; l_r[r] = 0.f; }
  #pragma unroll
  for (int f = 0; f < 4; ++f) Of[f] = zero;
  u16* PhW = Ph[wave];
  u16* PlW = Pl[wave];

  const int sr = tid >> 3, sc = ((tid & 7) ^ ((tid >> 3) & 7)) * 8;
  for (int kt = 0; kt < 16; ++kt) {
    __syncthreads();
    #pragma unroll
    for (int p = 0; p < 2; ++p) {
      const int row = p * 32 + sr;
      const size_t off = (size_t)(p * 256 + wave * 64) * 16;
      const size_t kg = ((size_t)b * 1024 + kt * 64 + row) * 3072 + 1024 + h * 64 + sc;
      gload16(QKh + kg, (char*)Kh + off);
      gload16(QKl + kg, (char*)Kl + off);
      const size_t vg = ((size_t)(b * 16 + h) * 64 + row) * 1024 + kt * 64 + sc;
      gload16(Vth + vg, (char*)Vh + off);
      gload16(Vtl + vg, (char*)Vl + off);
    }
    __syncthreads();
    float pm[4][4];
    #pragma unroll
    for (int jn = 0; jn < 4; ++jn) {
      floatx4 a = zero;
      #pragma unroll
      for (int kk = 0; kk < 2; ++kk) {
        const int n = jn * 16 + i15;
        const int ch = ((kk * 4 + quad) ^ (n & 7)) * 8;
        const short8 bh = *(const short8*)&Kh[n * 64 + ch];
        const short8 bl = *(const short8*)&Kl[n * 64 + ch];
        a = __builtin_amdgcn_mfma_f32_16x16x32_bf16(qh[kk], bh, a, 0, 0, 0);
        a = __builtin_amdgcn_mfma_f32_16x16x32_bf16(ql[kk], bh, a, 0, 0, 0);
        a = __builtin_amdgcn_mfma_f32_16x16x32_bf16(qh[kk], bl, a, 0, 0, 0);
      }
      #pragma unroll
      for (int r = 0; r < 4; ++r) pm[jn][r] = a[r] * stot[r];
    }
    float alpha[4];
    #pragma unroll
    for (int r = 0; r < 4; ++r) {
      float mx = fmaxf(fmaxf(pm[0][r], pm[1][r]), fmaxf(pm[2][r], pm[3][r]));
      mx = fmaxf(mx, __shfl_xor(mx, 1));
      mx = fmaxf(mx, __shfl_xor(mx, 2));
      mx = fmaxf(mx, __shfl_xor(mx, 4));
      mx = fmaxf(mx, __shfl_xor(mx, 8));
      const float mn = fmaxf(m_r[r], mx);
      alpha[r] = expf(m_r[r] - mn);
      m_r[r] = mn;
      float rs = 0.f;
      #pragma unroll
      for (int jn = 0; jn < 4; ++jn) { pm[jn][r] = expf(pm[jn][r] - mn); rs += pm[jn][r]; }
      rs += __shfl_xor(rs, 1);
      rs += __shfl_xor(rs, 2);
      rs += __shfl_xor(rs, 4);
      rs += __shfl_xor(rs, 8);
      l_r[r] = l_r[r] * alpha[r] + rs;
    }
    #pragma unroll
    for (int f = 0; f < 4; ++f)
      #pragma unroll
      for (int r = 0; r < 4; ++r) Of[f][r] *= alpha[r];
    #pragma unroll
    for (int jn = 0; jn < 4; ++jn)
      #pragma unroll
      for (int r = 0; r < 4; ++r) {
        const int a = (quad * 4 + r) * 72 + jn * 16 + i15;
        const u16 hh = f2bf(pm[jn][r]);
        PhW[a] = hh;
        PlW[a] = f2bf(pm[jn][r] - bf2f(hh));
      }
    #pragma unroll
    for (int kk = 0; kk < 2; ++kk) {
      const short8 pah = *(const short8*)&PhW[i15 * 72 + kk * 32 + quad * 8];
      const short8 pal = *(const short8*)&PlW[i15 * 72 + kk * 32 + quad * 8];
      #pragma unroll
      for (int f = 0; f < 4; ++f) {
        const int d = f * 16 + i15;
        const int ch = ((kk * 4 + quad) ^ (d & 7)) * 8;
        const short8 vbh = *(const short8*)&Vh[d * 64 + ch];
        const short8 vbl = *(const short8*)&Vl[d * 64 + ch];
        Of[f] = __builtin_amdgcn_mfma_f32_16x16x32_bf16(pah, vbh, Of[f], 0, 0, 0);
        Of[f] = __builtin_amdgcn_mfma_f32_16x16x32_bf16(pal, vbh, Of[f], 0, 0, 0);
        Of[f] = __builtin_amdgcn_mfma_f32_16x16x32_bf16(pah, vbl, Of[f], 0, 0, 0);
      }
    }
  }
  float inv[4];
  #pragma unroll
  for (int r = 0; r < 4; ++r) inv[r] = 1.f / l_r[r];
  #pragma unroll
  for (int f = 0; f < 4; ++f)
    #pragma unroll
    for (int r = 0; r < 4; ++r) {
      const size_t row = (size_t)b * 1024 + qt * 64 + wave * 16 + quad * 4 + r;
      const int col = h * 64 + f * 16 + i15;
      const float val = Of[f][r] * inv[r];
      AOf[row * 1024 + col] = val;
      const u16 hh = f2bf(val);
      AOh[row * 1024 + col] = hh;
      AOl[row * 1024 + col] = f2bf(val - bf2f(hh));
    }
}

// ---------------------------------------------------------------------------
// x = LN(a + b) * g + beta  -> fp32 out (+ optional bf16 copy for MFMA input)
// ---------------------------------------------------------------------------
template<bool BF>
__global__ __launch_bounds__(256) void ln_add_kernel(
    const float* __restrict__ A, const float* __restrict__ Bp,
    const float* __restrict__ g, const float* __restrict__ beta,
    float* __restrict__ outf, u16* __restrict__ outh) {
  int t = blockIdx.x, tid = threadIdx.x;
  const float* a = A + (size_t)t * DMODEL;
  const float* b = Bp + (size_t)t * DMODEL;
  float v[4]; float s = 0.f;
  #pragma unroll
  for (int i = 0; i < 4; ++i) { int d = tid + i*256; v[i] = a[d] + b[d]; s += v[i]; }
  s = blockReduceSum256(s);
  float mean = s * (1.f/1024.f);
  float q = 0.f;
  #pragma unroll
  for (int i = 0; i < 4; ++i) { float df = v[i]-mean; q += df*df; }
  q = blockReduceSum256(q);
  float rstd = rsqrtf(q*(1.f/1024.f) + 1e-5f);
  #pragma unroll
  for (int i = 0; i < 4; ++i) {
    int d = tid + i*256;
    float val = (v[i]-mean)*rstd*g[d] + beta[d];
    outf[(size_t)t*DMODEL + d] = val;
    if (BF) outh[(size_t)t*DMODEL + d] = f2bf(val);
  }
}

// ---------------------------------------------------------------------------
// Final fused kernel: y = (p0+p1 + b2[e])*rs[e] + x ; out = LN(x + y, n2)
// ---------------------------------------------------------------------------
__global__ __launch_bounds__(256) void ln_final_kernel(
    const float* __restrict__ X, const float* __restrict__ P0,
    const float* __restrict__ P1, const float* __restrict__ B2,
    const float* __restrict__ rsv, const int* __restrict__ e_sel,
    const float* __restrict__ g, const float* __restrict__ beta,
    float* __restrict__ out) {
  int t = blockIdx.x, tid = threadIdx.x;
  const int e = e_sel[t];
  const float rse = rsv[e];
  const float* b2e = B2 + (size_t)e * DMODEL;
  float v[4]; float s = 0.f;
  #pragma unroll
  for (int i = 0; i < 4; ++i) {
    int d = tid + i*256;
    const size_t idx = (size_t)t * DMODEL + d;
    const float xv = X[idx];
    const float yv = (P0[idx] + P1[idx] + b2e[d]) * rse + xv;
    v[i] = xv + yv;
    s += v[i];
  }
  s = blockReduceSum256(s);
  float mean = s * (1.f/1024.f);
  float q = 0.f;
  #pragma unroll
  for (int i = 0; i < 4; ++i) { float df = v[i]-mean; q += df*df; }
  q = blockReduceSum256(q);
  float rstd = rsqrtf(q*(1.f/1024.f) + 1e-5f);
  #pragma unroll
  for (int i = 0; i < 4; ++i) {
    int d = tid + i*256;
    out[(size_t)t*DMODEL + d] = (v[i]-mean)*rstd*g[d] + beta[d];
  }
}

// ---------------------------------------------------------------------------
// MoE router (fp32): e_sel = max index of top-2 logits.
// ---------------------------------------------------------------------------
__global__ __launch_bounds__(256) void moe_gate_kernel(
    const float* __restrict__ X, const float* __restrict__ gw,
    const float* __restrict__ gb, int* __restrict__ e_sel) {
  int wave = threadIdx.x >> 6, lane = threadIdx.x & 63;
  int token = blockIdx.x * 4 + wave;
  const float* x = X + (size_t)token * DMODEL;
  float acc[NEXP] = {};
  for (int d = lane; d < DMODEL; d += 64) {
    float xv = x[d];
    const float* gr = gw + (size_t)d * NEXP;
    #pragma unroll
    for (int e = 0; e < NEXP; ++e) acc[e] += xv * gr[e];
  }
  #pragma unroll
  for (int e = 0; e < NEXP; ++e) {
    #pragma unroll
    for (int off = 32; off; off >>= 1) acc[e] += __shfl_down(acc[e], off);
  }
  if (lane == 0) {
    float lg[NEXP];
    #pragma unroll
    for (int e = 0; e < NEXP; ++e) lg[e] = acc[e] + gb[e];
    int i1 = 0;
    for (int e = 1; e < NEXP; ++e) if (lg[e] > lg[i1]) i1 = e;
    int i2 = -1;
    for (int e = 0; e < NEXP; ++e) {
      if (e == i1) continue;
      if (i2 < 0 || lg[e] > lg[i2]) i2 = e;
    }
    e_sel[token] = (i1 > i2) ? i1 : i2;
  }
}

__global__ __launch_bounds__(256) void moe_group_kernel(
    const int* __restrict__ e_sel, int* __restrict__ perm,
    int* __restrict__ g_offs, int* __restrict__ g_counts) {
  __shared__ int cnt[NEXP], offs[NEXP], cur[NEXP];
  int tid = threadIdx.x;
  if (tid < NEXP) cnt[tid] = 0;
  __syncthreads();
  for (int t = tid; t < TOK; t += 256) atomicAdd(&cnt[e_sel[t]], 1);
  __syncthreads();
  if (tid == 0) {
    int run = 0;
    for (int e = 0; e < NEXP; ++e) { offs[e] = run; cur[e] = run; run += cnt[e]; }
  }
  __syncthreads();
  if (tid < NEXP) { g_offs[tid] = offs[tid]; g_counts[tid] = cnt[tid]; }
  for (int t = tid; t < TOK; t += 256) {
    int pos = atomicAdd(&cur[e_sel[t]], 1);
    perm[pos] = t;
  }
}

// LN over DFF (per selected expert) + exact-erf GELU, in place on bf16 h.
__global__ __launch_bounds__(256) void moe_ln_gelu_kernel(
    u16* __restrict__ H, const float* __restrict__ ln_g,
    const float* __restrict__ ln_b, const int* __restrict__ e_sel) {
  int t = blockIdx.x, tid = threadIdx.x;
  int e = e_sel[t];
  u16* h = H + (size_t)t * DFFN;
  float v[16]; float s = 0.f;
  #pragma unroll
  for (int i = 0; i < 16; ++i) { v[i] = bf2f(h[tid + i*256]); s += v[i]; }
  s = blockReduceSum256(s);
  float mean = s * (1.f/4096.f);
  float q = 0.f;
  #pragma unroll
  for (int i = 0; i < 16; ++i) { float df = v[i]-mean; q += df*df; }
  q = blockReduceSum256(q);
  float rstd = rsqrtf(q*(1.f/4096.f) + 1e-5f);
  const float* gg = ln_g + (size_t)e * DFFN;
  const float* bb = ln_b + (size_t)e * DFFN;
  #pragma unroll
  for (int i = 0; i < 16; ++i) {
    int d = tid + i*256;
    float x = (v[i]-mean)*rstd*gg[d] + bb[d];
    h[d] = f2bf(0.5f * x * (1.f + erff(x * 0.7071067811865475f)));
  }
}

// ---------------------------------------------------------------------------
extern "C" void kernel_launch(void* const* d_in, const int* in_sizes, int n_in,
                              void* d_out, int out_size, void* d_ws, size_t ws_size,
                              hipStream_t stream) {
  (void)in_sizes; (void)n_in; (void)out_size; (void)ws_size;
  const float* src    = (const float*)d_in[0];
  const float* qw     = (const float*)d_in[1];
  const float* kw     = (const float*)d_in[2];
  const float* vw     = (const float*)d_in[3];
  const float* ow     = (const float*)d_in[4];
  const float* gate_w = (const float*)d_in[5];
  const float* gate_b = (const float*)d_in[6];
  const float* scale_w= (const float*)d_in[7];
  const float* n1_g   = (const float*)d_in[8];
  const float* n1_b   = (const float*)d_in[9];
  const float* n2_g   = (const float*)d_in[10];
  const float* n2_b   = (const float*)d_in[11];
  const float* mgw    = (const float*)d_in[12];
  const float* mgb    = (const float*)d_in[13];
  const float* w1     = (const float*)d_in[14];
  const float* b1     = (const float*)d_in[15];
  const float* ln_g   = (const float*)d_in[16];
  const float* ln_b   = (const float*)d_in[17];
  const float* w2     = (const float*)d_in[18];
  const float* b2     = (const float*)d_in[19];
  const float* rs     = (const float*)d_in[20];

  char* ws = (char*)d_ws;
  const size_t MB = 1024 * 1024;
  // timeline-packed buffers (lifetimes annotated)
  u16*   qkv_hi = (u16*)(ws + 0*MB);    // 12 MB  [dead after attn]
  u16*   qkv_lo = (u16*)(ws + 12*MB);   // 12 MB
  u16*   Wt3_hi = (u16*)(ws + 24*MB);   // 6 MB   [QKV weights / reused per GEMM]
  u16*   Wt3_lo = (u16*)(ws + 30*MB);   // 6 MB
  u16*   Vt_hi  = (u16*)(ws + 36*MB);   // 4 MB   [dead after attn]
  u16*   Vt_lo  = (u16*)(ws + 40*MB);   // 4 MB
  u16*   src_hi = (u16*)(ws + 44*MB);   // 4 MB   [dead after QKV gemm]
  u16*   src_lo = (u16*)(ws + 48*MB);   // 4 MB
  float* ao     = (float*)(ws + 44*MB); // 8 MB   [written by attn, after src dead]
  u16*   ao_hi  = (u16*)(ws + 52*MB);   // 4 MB
  u16*   ao_lo  = (u16*)(ws + 56*MB);   // 4 MB
  u16*   gb_hi  = (u16*)(ws + 60*MB);   // 4 MB   [dead after ow gemm]
  u16*   gb_lo  = (u16*)(ws + 64*MB);   // 4 MB
  float* proj   = (float*)(ws + 0*MB);  // 8 MB   [qkv dead by then; dead after ln1]
  float* x      = (float*)(ws + 8*MB);  // 8 MB   [persists]
  u16*   x_hi   = (u16*)(ws + 16*MB);   // 4 MB   [dead after FFN1]
  u16*   WtA    = (u16*)(ws + 24*MB);   // 32 MB  [MoE weights; Wt3/Vt/ao dead]
  u16*   h      = (u16*)(ws + 56*MB);   // 16 MB  [ao_lo/gb dead]
  float* p0     = (float*)(ws + 0*MB);  // 8 MB   [FFN2 partial; proj dead]
  float* p1     = (float*)(ws + 72*MB); // 8 MB
  int*   e_sel  = (int*)(ws + 80*MB);
  int*   perm   = e_sel + TOK;
  int*   offs   = perm + TOK;
  int*   cnts   = offs + NEXP;

  dim3 blk(256);
  split_kernel<<<2048, blk, 0, stream>>>(src, src_hi, src_lo);

  // fused QKV: Wt3[3072][1024] <- qw|kw|vw; one 2048x3072x1024 split GEMM
  wt_conv_kernel<true><<<dim3(32,32,1), blk, 0, stream>>>(qw, Wt3_hi, Wt3_lo, DMODEL, DMODEL);
  wt_conv_kernel<true><<<dim3(32,32,1), blk, 0, stream>>>(kw, Wt3_hi + 1024*1024, Wt3_lo + 1024*1024, DMODEL, DMODEL);
  wt_conv_kernel<true><<<dim3(32,32,1), blk, 0, stream>>>(vw, Wt3_hi + 2048*1024, Wt3_lo + 2048*1024, DMODEL, DMODEL);
  gemm_split_kernel<2><<<dim3(48,16), blk, 0, stream>>>(src_hi, src_lo, Wt3_hi, Wt3_lo,
      nullptr, nullptr, nullptr, qkv_hi, qkv_lo, TOK, 3072, DMODEL);

  // V transpose + MFMA flash attention (split-bf16, dynamic scale gate)
  vt_trans_kernel<<<dim3(16,32), blk, 0, stream>>>(qkv_hi, qkv_lo, Vt_hi, Vt_lo);
  attn_mfma_kernel<<<dim3(16, NHEAD, 2), blk, 0, stream>>>(
      qkv_hi, qkv_lo, Vt_hi, Vt_lo, scale_w, ao, ao_hi, ao_lo);

  // gate = sigmoid(ao @ gate_w + gate_b); gbuf = ao * gate (split output)
  wt_conv_kernel<true><<<dim3(32,32,1), blk, 0, stream>>>(gate_w, Wt3_hi, Wt3_lo, DMODEL, DMODEL);
  gemm_split_kernel<1><<<dim3(16,16), blk, 0, stream>>>(ao_hi, ao_lo, Wt3_hi, Wt3_lo,
      gate_b, ao, nullptr, gb_hi, gb_lo, TOK, DMODEL, DMODEL);
  // proj = gbuf @ ow
  wt_conv_kernel<true><<<dim3(32,32,1), blk, 0, stream>>>(ow, Wt3_hi, Wt3_lo, DMODEL, DMODEL);
  gemm_split_kernel<0><<<dim3(16,16), blk, 0, stream>>>(gb_hi, gb_lo, Wt3_hi, Wt3_lo,
      nullptr, nullptr, proj, nullptr, nullptr, TOK, DMODEL, DMODEL);

  // x = LN(src + proj); bf16 copy for MoE A-side
  ln_add_kernel<true><<<TOK, blk, 0, stream>>>(src, proj, n1_g, n1_b, x, x_hi);

  // router (fp32) + grouping
  moe_gate_kernel<<<TOK/4, blk, 0, stream>>>(x, mgw, mgb, e_sel);
  moe_group_kernel<<<1, blk, 0, stream>>>(e_sel, perm, offs, cnts);

  // FFN1 in two expert-chunks (WtA = 32 MB holds 4 experts)
  for (int c = 0; c < 2; ++c) {
    wt_conv_kernel<false><<<dim3(DFFN/32, DMODEL/32, 4), blk, 0, stream>>>(
        w1 + (size_t)c*4*DMODEL*DFFN, WtA, nullptr, DMODEL, DFFN);
    gemm_moe_kernel<0><<<dim3(DFFN/64, 16, 4), blk, 0, stream>>>(
        x_hi, WtA, b1, perm, offs, cnts, h, nullptr, nullptr, DFFN, DMODEL, c*4);
  }
  moe_ln_gelu_kernel<<<TOK, blk, 0, stream>>>(h, ln_g, ln_b, e_sel);
  // FFN2 in two expert-chunks, 2-way split-K (z = ez + 4*ks) -> p0/p1
  for (int c = 0; c < 2; ++c) {
    wt_conv_kernel<false><<<dim3(DMODEL/32, DFFN/32, 4), blk, 0, stream>>>(
        w2 + (size_t)c*4*DFFN*DMODEL, WtA, nullptr, DFFN, DMODEL);
    gemm_moe_kernel<1><<<dim3(DMODEL/64, 16, 8), blk, 0, stream>>>(
        h, WtA, nullptr, perm, offs, cnts, nullptr, p0, p1, DMODEL, DFFN, c*4);
  }
  // out = LN(x + ((p0+p1+b2[e])*rs[e] + x), n2)
  ln_final_kernel<<<TOK, blk, 0, stream>>>(x, p0, p1, b2, rs, e_sel, n2_g, n2_b, (float*)d_out);
}